// Round 5
// baseline (365.034 us; speedup 1.0000x reference)
//
#include <hip/hip_runtime.h>
#include <hip/hip_bf16.h>
#include <math.h>

#define D_MODEL 1024
#define N_HEADS 16
#define HD 64
#define BB 2
#define TT 2048
#define MROWS (BB*TT)   // 4096

typedef __attribute__((ext_vector_type(8))) short short8;
typedef __attribute__((ext_vector_type(4))) float f32x4;

static __device__ __forceinline__ void gload16(const void* g, void* l) {
    __builtin_amdgcn_global_load_lds(
        (const __attribute__((address_space(1))) void*)g,
        (__attribute__((address_space(3))) void*)l, 16, 0, 0);
}

static __device__ __forceinline__ unsigned short f2bf(float f) {
    union { float f; unsigned u; } x; x.f = f;
    unsigned r = (x.u + 0x7fffu + ((x.u >> 16) & 1u)) >> 16;
    return (unsigned short)r;
}

// pack two f32 -> bf16x2 (round-half-up) in one v_perm
static __device__ __forceinline__ unsigned pack_bf16x2(float lo, float hi) {
    union { float f; unsigned u; } a, b; a.f = lo; b.f = hi;
    return __builtin_amdgcn_perm(b.u + 0x8000u, a.u + 0x8000u, 0x07060302u);
}

// ---------------------------------------------------------------------------
// Fused prep: blocks [0,1024) pack 4 weights (bf16, transposed);
// [1024,3072) cast x to bf16; block 3072 packs the qkv bias.
// ---------------------------------------------------------------------------
__global__ __launch_bounds__(256) void prep_kernel(
    const float* __restrict__ x,
    const float* __restrict__ Wq, const float* __restrict__ Wk,
    const float* __restrict__ Wv, const float* __restrict__ Wo,
    const float* __restrict__ bq, const float* __restrict__ bk,
    const float* __restrict__ bv,
    unsigned short* __restrict__ xb, unsigned short* __restrict__ Wqkvt,
    unsigned short* __restrict__ Wot, float* __restrict__ bqkv)
{
    __shared__ float Ts[64][65];
    const int bx = blockIdx.x, tid = threadIdx.x;
    if (bx < 1024) {
        const int z = bx >> 8, rem = bx & 255;
        const float* W = (z == 0) ? Wq : (z == 1) ? Wk : (z == 2) ? Wv : Wo;
        unsigned short* Wt = (z < 3) ? (Wqkvt + (size_t)z * 1024 * 1024) : Wot;
        const int n0 = (rem & 15) * 64, k0 = (rem >> 4) * 64;
#pragma unroll
        for (int i = 0; i < 16; ++i) {
            int lin = i * 256 + tid;
            int kl = lin >> 6, nl = lin & 63;
            Ts[nl][kl] = W[(size_t)(k0 + kl) * 1024 + n0 + nl];
        }
        __syncthreads();
#pragma unroll
        for (int i = 0; i < 16; ++i) {
            int lin = i * 256 + tid;
            int nl = lin >> 6, kl = lin & 63;
            Wt[(size_t)(n0 + nl) * 1024 + k0 + kl] = f2bf(Ts[nl][kl]);
        }
    } else if (bx < 3072) {
        int i = ((bx - 1024) * 256 + tid) * 8;
        float4 a = *(const float4*)(x + i);
        float4 b = *(const float4*)(x + i + 4);
        short8 o;
        o[0] = f2bf(a.x); o[1] = f2bf(a.y); o[2] = f2bf(a.z); o[3] = f2bf(a.w);
        o[4] = f2bf(b.x); o[5] = f2bf(b.y); o[6] = f2bf(b.z); o[7] = f2bf(b.w);
        *(short8*)(xb + i) = o;
    } else {
#pragma unroll
        for (int j = 0; j < 12; ++j) {
            int i = j * 256 + tid;
            float v = (i < 1024) ? bq[i] : ((i < 2048) ? bk[i - 1024] : bv[i - 2048]);
            bqkv[i] = v;
        }
    }
}

// ---------------------------------------------------------------------------
// MFMA GEMM (QKV): C[M][N] = A @ Bt^T + bias. 128x128 tile, BK=32, 4 waves.
// cols < qcols scaled by 0.125 (softmax fold). Block-cols >= 2048 are the V
// projection: written transposed to Vt[b][h][d][t] instead of C.
// ---------------------------------------------------------------------------
__global__ __launch_bounds__(256) void gemm_mfma_kernel(
    const unsigned short* __restrict__ A, const unsigned short* __restrict__ Bt,
    const float* __restrict__ bias, unsigned short* __restrict__ Cout,
    unsigned short* __restrict__ Vt, int N, int K, int qcols)
{
    __shared__ __align__(16) unsigned short As[128 * 32];
    __shared__ __align__(16) unsigned short Bs[128 * 32];

    const int tid  = threadIdx.x;
    const int lane = tid & 63;
    const int ln   = lane & 15;
    const int qd   = lane >> 4;
    const int w    = tid >> 6;
    const int wm   = w >> 1, wn = w & 1;

    const int lin  = blockIdx.y * gridDim.x + blockIdx.x;
    const int xcd  = lin & 7;
    const int slot = lin >> 3;
    const int sxw  = gridDim.x >> 1;
    const int syw  = ((gridDim.x * gridDim.y) >> 3) / sxw;
    const int sx   = slot % sxw, sy = slot / sxw;
    const int row0 = ((xcd >> 1) * syw + sy) * 128;
    const int col0 = ((xcd & 1) * sxw + sx) * 128;

    f32x4 acc[4][4];
#pragma unroll
    for (int mi = 0; mi < 4; ++mi)
#pragma unroll
        for (int ni = 0; ni < 4; ++ni)
            acc[mi][ni] = (f32x4){0.f, 0.f, 0.f, 0.f};

    const int s0 = tid, s1 = tid + 256;
    const int rA0 = s0 >> 2, cA0 = (s0 & 3) ^ ((rA0 >> 1) & 3);
    const int rA1 = s1 >> 2, cA1 = (s1 & 3) ^ ((rA1 >> 1) & 3);
    const unsigned short* Ag0 = A + (size_t)(row0 + rA0) * K + cA0 * 8;
    const unsigned short* Ag1 = A + (size_t)(row0 + rA1) * K + cA1 * 8;
    const unsigned short* Bg0 = Bt + (size_t)(col0 + rA0) * K + cA0 * 8;
    const unsigned short* Bg1 = Bt + (size_t)(col0 + rA1) * K + cA1 * 8;
    unsigned short* AsL0 = As + s0 * 8;
    unsigned short* AsL1 = As + s1 * 8;
    unsigned short* BsL0 = Bs + s0 * 8;
    unsigned short* BsL1 = Bs + s1 * 8;

    for (int kb = 0; kb < K; kb += 32) {
        if (kb) __syncthreads();
        gload16(Ag0 + kb, AsL0);
        gload16(Ag1 + kb, AsL1);
        gload16(Bg0 + kb, BsL0);
        gload16(Bg1 + kb, BsL1);
        __builtin_amdgcn_s_waitcnt(0);
        __syncthreads();

        short8 af[4], bf[4];
#pragma unroll
        for (int i = 0; i < 4; ++i) {
            int ra = wm * 64 + i * 16 + ln;
            int pa = ra * 4 + (qd ^ ((ra >> 1) & 3));
            af[i] = *(const short8*)(As + pa * 8);
            int rb = wn * 64 + i * 16 + ln;
            int pb = rb * 4 + (qd ^ ((rb >> 1) & 3));
            bf[i] = *(const short8*)(Bs + pb * 8);
        }
#pragma unroll
        for (int mi = 0; mi < 4; ++mi)
#pragma unroll
            for (int ni = 0; ni < 4; ++ni)
                acc[mi][ni] = __builtin_amdgcn_mfma_f32_16x16x32_bf16(
                    af[mi], bf[ni], acc[mi][ni], 0, 0, 0);
    }

    float bv[4];
#pragma unroll
    for (int ni = 0; ni < 4; ++ni)
        bv[ni] = bias[col0 + wn * 64 + ni * 16 + ln];

    if (col0 >= 2048) {
        const int h = ((col0 - 2048) >> 6) + wn;
#pragma unroll
        for (int mi = 0; mi < 4; ++mi) {
            int row = row0 + wm * 64 + mi * 16 + qd * 4;
            int b = row >> 11, t = row & 2047;
#pragma unroll
            for (int ni = 0; ni < 4; ++ni) {
                int d = ni * 16 + ln;
                float v0 = acc[mi][ni][0] + bv[ni];
                float v1 = acc[mi][ni][1] + bv[ni];
                float v2 = acc[mi][ni][2] + bv[ni];
                float v3 = acc[mi][ni][3] + bv[ni];
                unsigned u0 = pack_bf16x2(v0, v1);
                unsigned u1 = pack_bf16x2(v2, v3);
                *(uint2*)(Vt + (size_t)((b * 16 + h) * 64 + d) * TT + t) =
                    make_uint2(u0, u1);
            }
        }
    } else {
        float scl[4];
#pragma unroll
        for (int ni = 0; ni < 4; ++ni)
            scl[ni] = (col0 + wn * 64 + ni * 16 < qcols) ? 0.125f : 1.0f;
#pragma unroll
        for (int mi = 0; mi < 4; ++mi)
#pragma unroll
            for (int ni = 0; ni < 4; ++ni)
#pragma unroll
                for (int r = 0; r < 4; ++r) {
                    float v = (acc[mi][ni][r] + bv[ni]) * scl[ni];
                    int row = row0 + wm * 64 + mi * 16 + qd * 4 + r;
                    int col = col0 + wn * 64 + ni * 16 + ln;
                    Cout[(size_t)row * N + col] = f2bf(v);
                }
    }
}

// ---------------------------------------------------------------------------
// MFMA GEMM (output proj): 128x64 tile -> 512 blocks (2/CU). fp32 out.
// ---------------------------------------------------------------------------
__global__ __launch_bounds__(256) void gemm_mfma_n64_kernel(
    const unsigned short* __restrict__ A, const unsigned short* __restrict__ Bt,
    const float* __restrict__ bias, float* __restrict__ Cout, int N, int K)
{
    __shared__ __align__(16) unsigned short As[128 * 32];
    __shared__ __align__(16) unsigned short Bs[64 * 32];

    const int tid  = threadIdx.x;
    const int lane = tid & 63;
    const int ln   = lane & 15;
    const int qd   = lane >> 4;
    const int w    = tid >> 6;

    const int lin  = blockIdx.y * gridDim.x + blockIdx.x;
    const int xcd  = lin & 7;
    const int slot = lin >> 3;
    const int sxw  = gridDim.x >> 1;
    const int syw  = ((gridDim.x * gridDim.y) >> 3) / sxw;
    const int sx   = slot % sxw, sy = slot / sxw;
    const int row0 = ((xcd >> 1) * syw + sy) * 128;
    const int col0 = ((xcd & 1) * sxw + sx) * 64;

    f32x4 acc[2][4];
#pragma unroll
    for (int mi = 0; mi < 2; ++mi)
#pragma unroll
        for (int ni = 0; ni < 4; ++ni)
            acc[mi][ni] = (f32x4){0.f, 0.f, 0.f, 0.f};

    const int s0 = tid, s1 = tid + 256;
    const int rA0 = s0 >> 2, cA0 = (s0 & 3) ^ ((rA0 >> 1) & 3);
    const int rA1 = s1 >> 2, cA1 = (s1 & 3) ^ ((rA1 >> 1) & 3);
    const unsigned short* Ag0 = A + (size_t)(row0 + rA0) * K + cA0 * 8;
    const unsigned short* Ag1 = A + (size_t)(row0 + rA1) * K + cA1 * 8;
    const unsigned short* Bg0 = Bt + (size_t)(col0 + rA0) * K + cA0 * 8;
    unsigned short* AsL0 = As + s0 * 8;
    unsigned short* AsL1 = As + s1 * 8;
    unsigned short* BsL0 = Bs + s0 * 8;

    for (int kb = 0; kb < K; kb += 32) {
        if (kb) __syncthreads();
        gload16(Ag0 + kb, AsL0);
        gload16(Ag1 + kb, AsL1);
        gload16(Bg0 + kb, BsL0);
        __builtin_amdgcn_s_waitcnt(0);
        __syncthreads();

        short8 af[2], bf[4];
#pragma unroll
        for (int i = 0; i < 2; ++i) {
            int ra = w * 32 + i * 16 + ln;
            int pa = ra * 4 + (qd ^ ((ra >> 1) & 3));
            af[i] = *(const short8*)(As + pa * 8);
        }
#pragma unroll
        for (int i = 0; i < 4; ++i) {
            int rb = i * 16 + ln;
            int pb = rb * 4 + (qd ^ ((rb >> 1) & 3));
            bf[i] = *(const short8*)(Bs + pb * 8);
        }
#pragma unroll
        for (int mi = 0; mi < 2; ++mi)
#pragma unroll
            for (int ni = 0; ni < 4; ++ni)
                acc[mi][ni] = __builtin_amdgcn_mfma_f32_16x16x32_bf16(
                    af[mi], bf[ni], acc[mi][ni], 0, 0, 0);
    }

    float bv[4];
#pragma unroll
    for (int ni = 0; ni < 4; ++ni)
        bv[ni] = bias[col0 + ni * 16 + ln];

#pragma unroll
    for (int mi = 0; mi < 2; ++mi)
#pragma unroll
        for (int ni = 0; ni < 4; ++ni)
#pragma unroll
            for (int r = 0; r < 4; ++r) {
                int row = row0 + w * 32 + mi * 16 + qd * 4 + r;
                int col = col0 + ni * 16 + ln;
                Cout[(size_t)row * N + col] = acc[mi][ni][r] + bv[ni];
            }
}

// ---------------------------------------------------------------------------
// Flash attention: one 64-row q-tile per block, 1024 blocks (4/CU).
// XCD-locality swizzle: all tiles of a (b,h) share an XCD; heavy tiles first.
// Wave-independent key chunks, zero barriers in K-loop.
// ---------------------------------------------------------------------------
#define PSTRIDE 136
#define LDS_TOTAL (4*64*PSTRIDE + 2048)

__global__ __launch_bounds__(256, 4) void attn_mfma_kernel(
    const unsigned short* __restrict__ QKV,
    const unsigned short* __restrict__ Vt,
    unsigned short* __restrict__ Aout)
{
    __shared__ __align__(16) unsigned char lds[LDS_TOTAL];

    const int tid  = threadIdx.x;
    const int lane = tid & 63;
    const int ln   = lane & 15;
    const int qd   = lane >> 4;
    const int qd4  = qd * 4;
    const int w    = tid >> 6;

    // bx -> (b,h,qt): XCD = bx&7 pinned per bh; qt descending (heavy first)
    const int bx  = blockIdx.x;
    const int g   = bx >> 3;
    const int bh  = (bx & 7) + 8 * (g & 3);
    const int qt  = 31 - (g >> 2);
    const int b   = bh >> 4;
    const int h   = bh & 15;

    unsigned char* Pb   = lds + w * (64 * PSTRIDE);
    float*         Oacc = (float*)lds;
    float*         mlm  = (float*)(lds + 4 * 64 * PSTRIDE);
    float*         mll  = mlm + 256;

    const unsigned short* Kh = QKV + 1024 + h * 64;
    const unsigned short* Qh = QKV + h * 64;
    const unsigned short* Vh = Vt + (size_t)((b * 16 + h) * 64) * TT;

    short8 qa[4][2];
    {
        const unsigned short* Qb = Qh + (size_t)(b * TT + qt * 64) * 3072;
#pragma unroll
        for (int q4 = 0; q4 < 4; ++q4)
#pragma unroll
            for (int kk = 0; kk < 2; ++kk)
                qa[q4][kk] = *(const short8*)(Qb + (size_t)(q4 * 16 + ln) * 3072 + kk * 32 + qd * 8);
    }

    f32x4 O[4][4];
#pragma unroll
    for (int dt = 0; dt < 4; ++dt)
#pragma unroll
        for (int q4 = 0; q4 < 4; ++q4)
            O[dt][q4] = (f32x4){0.f, 0.f, 0.f, 0.f};
    float m_i[4] = {-1e30f, -1e30f, -1e30f, -1e30f};
    float l_i[4] = {0.f, 0.f, 0.f, 0.f};

    for (int kc = w; kc <= qt; kc += 4) {
        const unsigned short* Kc = Kh + (size_t)(b * TT + kc * 64) * 3072;
        const unsigned short* Vc = Vh + kc * 64;

        short8 kf[4][2], vf[4][2];
#pragma unroll
        for (int kt = 0; kt < 4; ++kt)
#pragma unroll
            for (int kk = 0; kk < 2; ++kk)
                kf[kt][kk] = *(const short8*)(Kc + (size_t)(kt * 16 + ln) * 3072 + kk * 32 + qd * 8);
#pragma unroll
        for (int dt = 0; dt < 4; ++dt)
#pragma unroll
            for (int kk = 0; kk < 2; ++kk)
                vf[dt][kk] = *(const short8*)(Vc + (size_t)(dt * 16 + ln) * TT + kk * 32 + qd * 8);

        f32x4 st[4][4];
#pragma unroll
        for (int kt = 0; kt < 4; ++kt)
#pragma unroll
            for (int q4 = 0; q4 < 4; ++q4) {
                f32x4 a = (f32x4){0.f, 0.f, 0.f, 0.f};
                a = __builtin_amdgcn_mfma_f32_16x16x32_bf16(kf[kt][0], qa[q4][0], a, 0, 0, 0);
                a = __builtin_amdgcn_mfma_f32_16x16x32_bf16(kf[kt][1], qa[q4][1], a, 0, 0, 0);
                st[kt][q4] = a;
            }

        if (kc == qt) {
#pragma unroll
            for (int kt = 0; kt < 4; ++kt)
#pragma unroll
                for (int q4 = 0; q4 < 4; ++q4)
#pragma unroll
                    for (int r = 0; r < 4; ++r)
                        if (kt * 16 + qd4 + r > q4 * 16 + ln)
                            st[kt][q4][r] = -1e30f;
        }

        float alpha[4];
#pragma unroll
        for (int q4 = 0; q4 < 4; ++q4) {
            float mx = st[0][q4][0];
#pragma unroll
            for (int kt = 0; kt < 4; ++kt)
#pragma unroll
                for (int r = 0; r < 4; ++r)
                    mx = fmaxf(mx, st[kt][q4][r]);
            mx = fmaxf(mx, __shfl_xor(mx, 16, 64));
            mx = fmaxf(mx, __shfl_xor(mx, 32, 64));
            float mn = fmaxf(m_i[q4], mx);
            alpha[q4] = __expf(m_i[q4] - mn);
            m_i[q4] = mn;
        }
#pragma unroll
        for (int kt = 0; kt < 4; ++kt)
#pragma unroll
            for (int q4 = 0; q4 < 4; ++q4)
#pragma unroll
                for (int r = 0; r < 4; ++r)
                    st[kt][q4][r] = __expf(st[kt][q4][r] - m_i[q4]);
#pragma unroll
        for (int q4 = 0; q4 < 4; ++q4) {
            float sm = 0.f;
#pragma unroll
            for (int kt = 0; kt < 4; ++kt)
#pragma unroll
                for (int r = 0; r < 4; ++r)
                    sm += st[kt][q4][r];
            sm += __shfl_xor(sm, 16, 64);
            sm += __shfl_xor(sm, 32, 64);
            l_i[q4] = l_i[q4] * alpha[q4] + sm;
        }
#pragma unroll
        for (int dt = 0; dt < 4; ++dt)
#pragma unroll
            for (int q4 = 0; q4 < 4; ++q4) {
                O[dt][q4][0] *= alpha[q4]; O[dt][q4][1] *= alpha[q4];
                O[dt][q4][2] *= alpha[q4]; O[dt][q4][3] *= alpha[q4];
            }

#pragma unroll
        for (int kt = 0; kt < 4; ++kt)
#pragma unroll
            for (int q4 = 0; q4 < 4; ++q4) {
                unsigned u0 = pack_bf16x2(st[kt][q4][0], st[kt][q4][1]);
                unsigned u1 = pack_bf16x2(st[kt][q4][2], st[kt][q4][3]);
                *(uint2*)(Pb + (q4 * 16 + ln) * PSTRIDE + kt * 32 + qd * 8) =
                    make_uint2(u0, u1);
            }

#pragma unroll
        for (int kk = 0; kk < 2; ++kk)
#pragma unroll
            for (int q4 = 0; q4 < 4; ++q4) {
                union { struct { uint2 a, b; } u; short8 s; } y;
                const unsigned char* yp = Pb + (q4 * 16 + ln) * PSTRIDE + kk * 64 + qd * 16;
                y.u.a = *(const uint2*)(yp);
                y.u.b = *(const uint2*)(yp + 8);
#pragma unroll
                for (int dt = 0; dt < 4; ++dt)
                    O[dt][q4] = __builtin_amdgcn_mfma_f32_16x16x32_bf16(
                        vf[dt][kk], y.s, O[dt][q4], 0, 0, 0);
            }
    }

    if (qd == 0) {
#pragma unroll
        for (int q4 = 0; q4 < 4; ++q4) {
            mlm[w * 64 + q4 * 16 + ln] = m_i[q4];
            mll[w * 64 + q4 * 16 + ln] = l_i[q4];
        }
    }
    __syncthreads();

    float fac[4];
#pragma unroll
    for (int q4 = 0; q4 < 4; ++q4) {
        int q = q4 * 16 + ln;
        float m0 = mlm[q], m1 = mlm[64 + q], m2 = mlm[128 + q], m3 = mlm[192 + q];
        float M = fmaxf(fmaxf(m0, m1), fmaxf(m2, m3));
        float f0 = __expf(m0 - M), f1 = __expf(m1 - M);
        float f2 = __expf(m2 - M), f3 = __expf(m3 - M);
        float L = f0 * mll[q] + f1 * mll[64 + q] + f2 * mll[128 + q] + f3 * mll[192 + q];
        float myf = (w == 0) ? f0 : (w == 1) ? f1 : (w == 2) ? f2 : f3;
        fac[q4] = myf / L;
    }
#pragma unroll
    for (int dt = 0; dt < 4; ++dt)
#pragma unroll
        for (int q4 = 0; q4 < 4; ++q4) {
            O[dt][q4][0] *= fac[q4]; O[dt][q4][1] *= fac[q4];
            O[dt][q4][2] *= fac[q4]; O[dt][q4][3] *= fac[q4];
        }

    for (int wv = 0; wv < 4; ++wv) {
        if (w == wv) {
#pragma unroll
            for (int dt = 0; dt < 4; ++dt)
#pragma unroll
                for (int q4 = 0; q4 < 4; ++q4) {
                    float* pp = Oacc + (q4 * 16 + ln) * 68 + dt * 16 + qd4;
                    if (wv == 0) {
                        *(f32x4*)pp = O[dt][q4];
                    } else {
                        f32x4 t = *(const f32x4*)pp;
                        t += O[dt][q4];
                        *(f32x4*)pp = t;
                    }
                }
        }
        __syncthreads();
    }

    {
        int q = tid >> 2, dg = tid & 3;
        const float* rowp = Oacc + q * 68 + dg * 16;
        short8 s0v, s1v;
#pragma unroll
        for (int i = 0; i < 8; ++i) {
            s0v[i] = f2bf(rowp[i]);
            s1v[i] = f2bf(rowp[8 + i]);
        }
        size_t orow = (size_t)(b * TT + qt * 64 + q) * D_MODEL + h * 64 + dg * 16;
        *(short8*)(Aout + orow) = s0v;
        *(short8*)(Aout + orow + 8) = s1v;
    }
}

// ---------------------------------------------------------------------------
extern "C" void kernel_launch(void* const* d_in, const int* in_sizes, int n_in,
                              void* d_out, int out_size, void* d_ws, size_t ws_size,
                              hipStream_t stream) {
    const float* x  = (const float*)d_in[0];
    const float* Wq = (const float*)d_in[2];
    const float* bq = (const float*)d_in[3];
    const float* Wk = (const float*)d_in[4];
    const float* bk = (const float*)d_in[5];
    const float* Wv = (const float*)d_in[6];
    const float* bv = (const float*)d_in[7];
    const float* Wo = (const float*)d_in[8];
    const float* bo = (const float*)d_in[9];
    float* out = (float*)d_out;

    uint8_t* w8 = (uint8_t*)d_ws;
    const size_t MB = 1024 * 1024;
    unsigned short* xb    = (unsigned short*)(w8);                 // 8 MB [4096][1024]
    unsigned short* Wqkvt = (unsigned short*)(w8 + 8 * MB);        // 6 MB [3072][1024]
    unsigned short* Wot   = (unsigned short*)(w8 + 14 * MB);       // 2 MB [1024][1024]
    float*          bqkv  = (float*)(w8 + 16 * MB);                // 12 KB
    unsigned short* QKV   = (unsigned short*)(w8 + 17 * MB);       // 24 MB [4096][3072] (V region unused)
    unsigned short* Vt    = (unsigned short*)(w8 + 41 * MB);       // 8 MB [2][16][64][2048]
    unsigned short* Aout  = (unsigned short*)(w8 + 49 * MB);       // 8 MB [4096][1024]

    prep_kernel<<<3073, 256, 0, stream>>>(x, Wq, Wk, Wv, Wo, bq, bk, bv,
                                          xb, Wqkvt, Wot, bqkv);
    gemm_mfma_kernel<<<dim3(24, 32), 256, 0, stream>>>(xb, Wqkvt, bqkv, QKV, Vt,
                                                       3072, 1024, 1024);
    attn_mfma_kernel<<<1024, 256, 0, stream>>>(QKV, Vt, Aout);
    gemm_mfma_n64_kernel<<<dim3(16, 32), 256, 0, stream>>>(Aout, Wot, bo, out,
                                                           1024, 1024);
}

// Round 6
// 284.276 us; speedup vs baseline: 1.2841x; 1.2841x over previous
//
#include <hip/hip_runtime.h>
#include <hip/hip_bf16.h>
#include <math.h>

#define D_MODEL 1024
#define N_HEADS 16
#define HD 64
#define BB 2
#define TT 2048
#define MROWS (BB*TT)   // 4096

typedef __attribute__((ext_vector_type(8))) short short8;
typedef __attribute__((ext_vector_type(4))) float f32x4;

static __device__ __forceinline__ void gload16(const void* g, void* l) {
    __builtin_amdgcn_global_load_lds(
        (const __attribute__((address_space(1))) void*)g,
        (__attribute__((address_space(3))) void*)l, 16, 0, 0);
}

static __device__ __forceinline__ unsigned short f2bf(float f) {
    union { float f; unsigned u; } x; x.f = f;
    unsigned r = (x.u + 0x7fffu + ((x.u >> 16) & 1u)) >> 16;
    return (unsigned short)r;
}

// pack two f32 -> bf16x2 (round-half-up) in one v_perm
static __device__ __forceinline__ unsigned pack_bf16x2(float lo, float hi) {
    union { float f; unsigned u; } a, b; a.f = lo; b.f = hi;
    return __builtin_amdgcn_perm(b.u + 0x8000u, a.u + 0x8000u, 0x07060302u);
}

// ---------------------------------------------------------------------------
// Fused prep: blocks [0,1024) pack 4 weights (bf16, transposed);
// [1024,3072) cast x to bf16; block 3072 packs the qkv bias.
// ---------------------------------------------------------------------------
__global__ __launch_bounds__(256) void prep_kernel(
    const float* __restrict__ x,
    const float* __restrict__ Wq, const float* __restrict__ Wk,
    const float* __restrict__ Wv, const float* __restrict__ Wo,
    const float* __restrict__ bq, const float* __restrict__ bk,
    const float* __restrict__ bv,
    unsigned short* __restrict__ xb, unsigned short* __restrict__ Wqkvt,
    unsigned short* __restrict__ Wot, float* __restrict__ bqkv)
{
    __shared__ float Ts[64][65];
    const int bx = blockIdx.x, tid = threadIdx.x;
    if (bx < 1024) {
        const int z = bx >> 8, rem = bx & 255;
        const float* W = (z == 0) ? Wq : (z == 1) ? Wk : (z == 2) ? Wv : Wo;
        unsigned short* Wt = (z < 3) ? (Wqkvt + (size_t)z * 1024 * 1024) : Wot;
        const int n0 = (rem & 15) * 64, k0 = (rem >> 4) * 64;
#pragma unroll
        for (int i = 0; i < 16; ++i) {
            int lin = i * 256 + tid;
            int kl = lin >> 6, nl = lin & 63;
            Ts[nl][kl] = W[(size_t)(k0 + kl) * 1024 + n0 + nl];
        }
        __syncthreads();
#pragma unroll
        for (int i = 0; i < 16; ++i) {
            int lin = i * 256 + tid;
            int nl = lin >> 6, kl = lin & 63;
            Wt[(size_t)(n0 + nl) * 1024 + k0 + kl] = f2bf(Ts[nl][kl]);
        }
    } else if (bx < 3072) {
        int i = ((bx - 1024) * 256 + tid) * 8;
        float4 a = *(const float4*)(x + i);
        float4 b = *(const float4*)(x + i + 4);
        short8 o;
        o[0] = f2bf(a.x); o[1] = f2bf(a.y); o[2] = f2bf(a.z); o[3] = f2bf(a.w);
        o[4] = f2bf(b.x); o[5] = f2bf(b.y); o[6] = f2bf(b.z); o[7] = f2bf(b.w);
        *(short8*)(xb + i) = o;
    } else {
#pragma unroll
        for (int j = 0; j < 12; ++j) {
            int i = j * 256 + tid;
            float v = (i < 1024) ? bq[i] : ((i < 2048) ? bk[i - 1024] : bv[i - 2048]);
            bqkv[i] = v;
        }
    }
}

// ---------------------------------------------------------------------------
// MFMA GEMM (QKV): C[M][N] = A @ Bt^T + bias. 128x128 tile, BK=32, 4 waves.
// cols < qcols scaled by 0.125 (softmax fold). Block-cols >= 2048 are the V
// projection: written transposed to Vt[b][h][d][t] instead of C.
// ---------------------------------------------------------------------------
__global__ __launch_bounds__(256) void gemm_mfma_kernel(
    const unsigned short* __restrict__ A, const unsigned short* __restrict__ Bt,
    const float* __restrict__ bias, unsigned short* __restrict__ Cout,
    unsigned short* __restrict__ Vt, int N, int K, int qcols)
{
    __shared__ __align__(16) unsigned short As[128 * 32];
    __shared__ __align__(16) unsigned short Bs[128 * 32];

    const int tid  = threadIdx.x;
    const int lane = tid & 63;
    const int ln   = lane & 15;
    const int qd   = lane >> 4;
    const int w    = tid >> 6;
    const int wm   = w >> 1, wn = w & 1;

    const int lin  = blockIdx.y * gridDim.x + blockIdx.x;
    const int xcd  = lin & 7;
    const int slot = lin >> 3;
    const int sxw  = gridDim.x >> 1;
    const int syw  = ((gridDim.x * gridDim.y) >> 3) / sxw;
    const int sx   = slot % sxw, sy = slot / sxw;
    const int row0 = ((xcd >> 1) * syw + sy) * 128;
    const int col0 = ((xcd & 1) * sxw + sx) * 128;

    f32x4 acc[4][4];
#pragma unroll
    for (int mi = 0; mi < 4; ++mi)
#pragma unroll
        for (int ni = 0; ni < 4; ++ni)
            acc[mi][ni] = (f32x4){0.f, 0.f, 0.f, 0.f};

    const int s0 = tid, s1 = tid + 256;
    const int rA0 = s0 >> 2, cA0 = (s0 & 3) ^ ((rA0 >> 1) & 3);
    const int rA1 = s1 >> 2, cA1 = (s1 & 3) ^ ((rA1 >> 1) & 3);
    const unsigned short* Ag0 = A + (size_t)(row0 + rA0) * K + cA0 * 8;
    const unsigned short* Ag1 = A + (size_t)(row0 + rA1) * K + cA1 * 8;
    const unsigned short* Bg0 = Bt + (size_t)(col0 + rA0) * K + cA0 * 8;
    const unsigned short* Bg1 = Bt + (size_t)(col0 + rA1) * K + cA1 * 8;
    unsigned short* AsL0 = As + s0 * 8;
    unsigned short* AsL1 = As + s1 * 8;
    unsigned short* BsL0 = Bs + s0 * 8;
    unsigned short* BsL1 = Bs + s1 * 8;

    for (int kb = 0; kb < K; kb += 32) {
        if (kb) __syncthreads();
        gload16(Ag0 + kb, AsL0);
        gload16(Ag1 + kb, AsL1);
        gload16(Bg0 + kb, BsL0);
        gload16(Bg1 + kb, BsL1);
        __builtin_amdgcn_s_waitcnt(0);
        __syncthreads();

        short8 af[4], bf[4];
#pragma unroll
        for (int i = 0; i < 4; ++i) {
            int ra = wm * 64 + i * 16 + ln;
            int pa = ra * 4 + (qd ^ ((ra >> 1) & 3));
            af[i] = *(const short8*)(As + pa * 8);
            int rb = wn * 64 + i * 16 + ln;
            int pb = rb * 4 + (qd ^ ((rb >> 1) & 3));
            bf[i] = *(const short8*)(Bs + pb * 8);
        }
#pragma unroll
        for (int mi = 0; mi < 4; ++mi)
#pragma unroll
            for (int ni = 0; ni < 4; ++ni)
                acc[mi][ni] = __builtin_amdgcn_mfma_f32_16x16x32_bf16(
                    af[mi], bf[ni], acc[mi][ni], 0, 0, 0);
    }

    float bv[4];
#pragma unroll
    for (int ni = 0; ni < 4; ++ni)
        bv[ni] = bias[col0 + wn * 64 + ni * 16 + ln];

    if (col0 >= 2048) {
        const int h = ((col0 - 2048) >> 6) + wn;
#pragma unroll
        for (int mi = 0; mi < 4; ++mi) {
            int row = row0 + wm * 64 + mi * 16 + qd * 4;
            int b = row >> 11, t = row & 2047;
#pragma unroll
            for (int ni = 0; ni < 4; ++ni) {
                int d = ni * 16 + ln;
                float v0 = acc[mi][ni][0] + bv[ni];
                float v1 = acc[mi][ni][1] + bv[ni];
                float v2 = acc[mi][ni][2] + bv[ni];
                float v3 = acc[mi][ni][3] + bv[ni];
                unsigned u0 = pack_bf16x2(v0, v1);
                unsigned u1 = pack_bf16x2(v2, v3);
                *(uint2*)(Vt + (size_t)((b * 16 + h) * 64 + d) * TT + t) =
                    make_uint2(u0, u1);
            }
        }
    } else {
        float scl[4];
#pragma unroll
        for (int ni = 0; ni < 4; ++ni)
            scl[ni] = (col0 + wn * 64 + ni * 16 < qcols) ? 0.125f : 1.0f;
#pragma unroll
        for (int mi = 0; mi < 4; ++mi)
#pragma unroll
            for (int ni = 0; ni < 4; ++ni)
#pragma unroll
                for (int r = 0; r < 4; ++r) {
                    float v = (acc[mi][ni][r] + bv[ni]) * scl[ni];
                    int row = row0 + wm * 64 + mi * 16 + qd * 4 + r;
                    int col = col0 + wn * 64 + ni * 16 + ln;
                    Cout[(size_t)row * N + col] = f2bf(v);
                }
    }
}

// ---------------------------------------------------------------------------
// MFMA GEMM (output proj): 128x64 tile -> 512 blocks (2/CU). fp32 out.
// ---------------------------------------------------------------------------
__global__ __launch_bounds__(256) void gemm_mfma_n64_kernel(
    const unsigned short* __restrict__ A, const unsigned short* __restrict__ Bt,
    const float* __restrict__ bias, float* __restrict__ Cout, int N, int K)
{
    __shared__ __align__(16) unsigned short As[128 * 32];
    __shared__ __align__(16) unsigned short Bs[64 * 32];

    const int tid  = threadIdx.x;
    const int lane = tid & 63;
    const int ln   = lane & 15;
    const int qd   = lane >> 4;
    const int w    = tid >> 6;

    const int lin  = blockIdx.y * gridDim.x + blockIdx.x;
    const int xcd  = lin & 7;
    const int slot = lin >> 3;
    const int sxw  = gridDim.x >> 1;
    const int syw  = ((gridDim.x * gridDim.y) >> 3) / sxw;
    const int sx   = slot % sxw, sy = slot / sxw;
    const int row0 = ((xcd >> 1) * syw + sy) * 128;
    const int col0 = ((xcd & 1) * sxw + sx) * 64;

    f32x4 acc[2][4];
#pragma unroll
    for (int mi = 0; mi < 2; ++mi)
#pragma unroll
        for (int ni = 0; ni < 4; ++ni)
            acc[mi][ni] = (f32x4){0.f, 0.f, 0.f, 0.f};

    const int s0 = tid, s1 = tid + 256;
    const int rA0 = s0 >> 2, cA0 = (s0 & 3) ^ ((rA0 >> 1) & 3);
    const int rA1 = s1 >> 2, cA1 = (s1 & 3) ^ ((rA1 >> 1) & 3);
    const unsigned short* Ag0 = A + (size_t)(row0 + rA0) * K + cA0 * 8;
    const unsigned short* Ag1 = A + (size_t)(row0 + rA1) * K + cA1 * 8;
    const unsigned short* Bg0 = Bt + (size_t)(col0 + rA0) * K + cA0 * 8;
    unsigned short* AsL0 = As + s0 * 8;
    unsigned short* AsL1 = As + s1 * 8;
    unsigned short* BsL0 = Bs + s0 * 8;

    for (int kb = 0; kb < K; kb += 32) {
        if (kb) __syncthreads();
        gload16(Ag0 + kb, AsL0);
        gload16(Ag1 + kb, AsL1);
        gload16(Bg0 + kb, BsL0);
        __builtin_amdgcn_s_waitcnt(0);
        __syncthreads();

        short8 af[2], bf[4];
#pragma unroll
        for (int i = 0; i < 2; ++i) {
            int ra = w * 32 + i * 16 + ln;
            int pa = ra * 4 + (qd ^ ((ra >> 1) & 3));
            af[i] = *(const short8*)(As + pa * 8);
        }
#pragma unroll
        for (int i = 0; i < 4; ++i) {
            int rb = i * 16 + ln;
            int pb = rb * 4 + (qd ^ ((rb >> 1) & 3));
            bf[i] = *(const short8*)(Bs + pb * 8);
        }
#pragma unroll
        for (int mi = 0; mi < 2; ++mi)
#pragma unroll
            for (int ni = 0; ni < 4; ++ni)
                acc[mi][ni] = __builtin_amdgcn_mfma_f32_16x16x32_bf16(
                    af[mi], bf[ni], acc[mi][ni], 0, 0, 0);
    }

    float bv[4];
#pragma unroll
    for (int ni = 0; ni < 4; ++ni)
        bv[ni] = bias[col0 + ni * 16 + ln];

#pragma unroll
    for (int mi = 0; mi < 2; ++mi)
#pragma unroll
        for (int ni = 0; ni < 4; ++ni)
#pragma unroll
            for (int r = 0; r < 4; ++r) {
                int row = row0 + w * 32 + mi * 16 + qd * 4 + r;
                int col = col0 + ni * 16 + ln;
                Cout[(size_t)row * N + col] = acc[mi][ni][r] + bv[ni];
            }
}

// ---------------------------------------------------------------------------
// Flash attention: one 64-row q-tile per block, 1024 blocks.
// __launch_bounds__(256,3): 3 blocks/CU, VGPR cap 170 (no spill; 124 natural).
// XCD-locality swizzle: all tiles of a (b,h) share an XCD; heavy tiles first.
// Wave-independent key chunks, zero barriers in K-loop.
// ---------------------------------------------------------------------------
#define PSTRIDE 136
#define LDS_TOTAL (4*64*PSTRIDE + 2048)

__global__ __launch_bounds__(256, 3) void attn_mfma_kernel(
    const unsigned short* __restrict__ QKV,
    const unsigned short* __restrict__ Vt,
    unsigned short* __restrict__ Aout)
{
    __shared__ __align__(16) unsigned char lds[LDS_TOTAL];

    const int tid  = threadIdx.x;
    const int lane = tid & 63;
    const int ln   = lane & 15;
    const int qd   = lane >> 4;
    const int qd4  = qd * 4;
    const int w    = tid >> 6;

    // bx -> (b,h,qt): XCD = bx&7 pinned per bh; qt descending (heavy first)
    const int bx  = blockIdx.x;
    const int g   = bx >> 3;
    const int bh  = (bx & 7) + 8 * (g & 3);
    const int qt  = 31 - (g >> 2);
    const int b   = bh >> 4;
    const int h   = bh & 15;

    unsigned char* Pb   = lds + w * (64 * PSTRIDE);
    float*         Oacc = (float*)lds;
    float*         mlm  = (float*)(lds + 4 * 64 * PSTRIDE);
    float*         mll  = mlm + 256;

    const unsigned short* Kh = QKV + 1024 + h * 64;
    const unsigned short* Qh = QKV + h * 64;
    const unsigned short* Vh = Vt + (size_t)((b * 16 + h) * 64) * TT;

    short8 qa[4][2];
    {
        const unsigned short* Qb = Qh + (size_t)(b * TT + qt * 64) * 3072;
#pragma unroll
        for (int q4 = 0; q4 < 4; ++q4)
#pragma unroll
            for (int kk = 0; kk < 2; ++kk)
                qa[q4][kk] = *(const short8*)(Qb + (size_t)(q4 * 16 + ln) * 3072 + kk * 32 + qd * 8);
    }

    f32x4 O[4][4];
#pragma unroll
    for (int dt = 0; dt < 4; ++dt)
#pragma unroll
        for (int q4 = 0; q4 < 4; ++q4)
            O[dt][q4] = (f32x4){0.f, 0.f, 0.f, 0.f};
    float m_i[4] = {-1e30f, -1e30f, -1e30f, -1e30f};
    float l_i[4] = {0.f, 0.f, 0.f, 0.f};

    for (int kc = w; kc <= qt; kc += 4) {
        const unsigned short* Kc = Kh + (size_t)(b * TT + kc * 64) * 3072;
        const unsigned short* Vc = Vh + kc * 64;

        short8 kf[4][2], vf[4][2];
#pragma unroll
        for (int kt = 0; kt < 4; ++kt)
#pragma unroll
            for (int kk = 0; kk < 2; ++kk)
                kf[kt][kk] = *(const short8*)(Kc + (size_t)(kt * 16 + ln) * 3072 + kk * 32 + qd * 8);
#pragma unroll
        for (int dt = 0; dt < 4; ++dt)
#pragma unroll
            for (int kk = 0; kk < 2; ++kk)
                vf[dt][kk] = *(const short8*)(Vc + (size_t)(dt * 16 + ln) * TT + kk * 32 + qd * 8);

        f32x4 st[4][4];
#pragma unroll
        for (int kt = 0; kt < 4; ++kt)
#pragma unroll
            for (int q4 = 0; q4 < 4; ++q4) {
                f32x4 a = (f32x4){0.f, 0.f, 0.f, 0.f};
                a = __builtin_amdgcn_mfma_f32_16x16x32_bf16(kf[kt][0], qa[q4][0], a, 0, 0, 0);
                a = __builtin_amdgcn_mfma_f32_16x16x32_bf16(kf[kt][1], qa[q4][1], a, 0, 0, 0);
                st[kt][q4] = a;
            }

        if (kc == qt) {
#pragma unroll
            for (int kt = 0; kt < 4; ++kt)
#pragma unroll
                for (int q4 = 0; q4 < 4; ++q4)
#pragma unroll
                    for (int r = 0; r < 4; ++r)
                        if (kt * 16 + qd4 + r > q4 * 16 + ln)
                            st[kt][q4][r] = -1e30f;
        }

        float alpha[4];
#pragma unroll
        for (int q4 = 0; q4 < 4; ++q4) {
            float mx = st[0][q4][0];
#pragma unroll
            for (int kt = 0; kt < 4; ++kt)
#pragma unroll
                for (int r = 0; r < 4; ++r)
                    mx = fmaxf(mx, st[kt][q4][r]);
            mx = fmaxf(mx, __shfl_xor(mx, 16, 64));
            mx = fmaxf(mx, __shfl_xor(mx, 32, 64));
            float mn = fmaxf(m_i[q4], mx);
            alpha[q4] = __expf(m_i[q4] - mn);
            m_i[q4] = mn;
        }
#pragma unroll
        for (int kt = 0; kt < 4; ++kt)
#pragma unroll
            for (int q4 = 0; q4 < 4; ++q4)
#pragma unroll
                for (int r = 0; r < 4; ++r)
                    st[kt][q4][r] = __expf(st[kt][q4][r] - m_i[q4]);
#pragma unroll
        for (int q4 = 0; q4 < 4; ++q4) {
            float sm = 0.f;
#pragma unroll
            for (int kt = 0; kt < 4; ++kt)
#pragma unroll
                for (int r = 0; r < 4; ++r)
                    sm += st[kt][q4][r];
            sm += __shfl_xor(sm, 16, 64);
            sm += __shfl_xor(sm, 32, 64);
            l_i[q4] = l_i[q4] * alpha[q4] + sm;
        }
#pragma unroll
        for (int dt = 0; dt < 4; ++dt)
#pragma unroll
            for (int q4 = 0; q4 < 4; ++q4) {
                O[dt][q4][0] *= alpha[q4]; O[dt][q4][1] *= alpha[q4];
                O[dt][q4][2] *= alpha[q4]; O[dt][q4][3] *= alpha[q4];
            }

#pragma unroll
        for (int kt = 0; kt < 4; ++kt)
#pragma unroll
            for (int q4 = 0; q4 < 4; ++q4) {
                unsigned u0 = pack_bf16x2(st[kt][q4][0], st[kt][q4][1]);
                unsigned u1 = pack_bf16x2(st[kt][q4][2], st[kt][q4][3]);
                *(uint2*)(Pb + (q4 * 16 + ln) * PSTRIDE + kt * 32 + qd * 8) =
                    make_uint2(u0, u1);
            }

#pragma unroll
        for (int kk = 0; kk < 2; ++kk)
#pragma unroll
            for (int q4 = 0; q4 < 4; ++q4) {
                union { struct { uint2 a, b; } u; short8 s; } y;
                const unsigned char* yp = Pb + (q4 * 16 + ln) * PSTRIDE + kk * 64 + qd * 16;
                y.u.a = *(const uint2*)(yp);
                y.u.b = *(const uint2*)(yp + 8);
#pragma unroll
                for (int dt = 0; dt < 4; ++dt)
                    O[dt][q4] = __builtin_amdgcn_mfma_f32_16x16x32_bf16(
                        vf[dt][kk], y.s, O[dt][q4], 0, 0, 0);
            }
    }

    if (qd == 0) {
#pragma unroll
        for (int q4 = 0; q4 < 4; ++q4) {
            mlm[w * 64 + q4 * 16 + ln] = m_i[q4];
            mll[w * 64 + q4 * 16 + ln] = l_i[q4];
        }
    }
    __syncthreads();

    float fac[4];
#pragma unroll
    for (int q4 = 0; q4 < 4; ++q4) {
        int q = q4 * 16 + ln;
        float m0 = mlm[q], m1 = mlm[64 + q], m2 = mlm[128 + q], m3 = mlm[192 + q];
        float M = fmaxf(fmaxf(m0, m1), fmaxf(m2, m3));
        float f0 = __expf(m0 - M), f1 = __expf(m1 - M);
        float f2 = __expf(m2 - M), f3 = __expf(m3 - M);
        float L = f0 * mll[q] + f1 * mll[64 + q] + f2 * mll[128 + q] + f3 * mll[192 + q];
        float myf = (w == 0) ? f0 : (w == 1) ? f1 : (w == 2) ? f2 : f3;
        fac[q4] = myf / L;
    }
#pragma unroll
    for (int dt = 0; dt < 4; ++dt)
#pragma unroll
        for (int q4 = 0; q4 < 4; ++q4) {
            O[dt][q4][0] *= fac[q4]; O[dt][q4][1] *= fac[q4];
            O[dt][q4][2] *= fac[q4]; O[dt][q4][3] *= fac[q4];
        }

    for (int wv = 0; wv < 4; ++wv) {
        if (w == wv) {
#pragma unroll
            for (int dt = 0; dt < 4; ++dt)
#pragma unroll
                for (int q4 = 0; q4 < 4; ++q4) {
                    float* pp = Oacc + (q4 * 16 + ln) * 68 + dt * 16 + qd4;
                    if (wv == 0) {
                        *(f32x4*)pp = O[dt][q4];
                    } else {
                        f32x4 t = *(const f32x4*)pp;
                        t += O[dt][q4];
                        *(f32x4*)pp = t;
                    }
                }
        }
        __syncthreads();
    }

    {
        int q = tid >> 2, dg = tid & 3;
        const float* rowp = Oacc + q * 68 + dg * 16;
        short8 s0v, s1v;
#pragma unroll
        for (int i = 0; i < 8; ++i) {
            s0v[i] = f2bf(rowp[i]);
            s1v[i] = f2bf(rowp[8 + i]);
        }
        size_t orow = (size_t)(b * TT + qt * 64 + q) * D_MODEL + h * 64 + dg * 16;
        *(short8*)(Aout + orow) = s0v;
        *(short8*)(Aout + orow + 8) = s1v;
    }
}

// ---------------------------------------------------------------------------
extern "C" void kernel_launch(void* const* d_in, const int* in_sizes, int n_in,
                              void* d_out, int out_size, void* d_ws, size_t ws_size,
                              hipStream_t stream) {
    const float* x  = (const float*)d_in[0];
    const float* Wq = (const float*)d_in[2];
    const float* bq = (const float*)d_in[3];
    const float* Wk = (const float*)d_in[4];
    const float* bk = (const float*)d_in[5];
    const float* Wv = (const float*)d_in[6];
    const float* bv = (const float*)d_in[7];
    const float* Wo = (const float*)d_in[8];
    const float* bo = (const float*)d_in[9];
    float* out = (float*)d_out;

    uint8_t* w8 = (uint8_t*)d_ws;
    const size_t MB = 1024 * 1024;
    unsigned short* xb    = (unsigned short*)(w8);                 // 8 MB [4096][1024]
    unsigned short* Wqkvt = (unsigned short*)(w8 + 8 * MB);        // 6 MB [3072][1024]
    unsigned short* Wot   = (unsigned short*)(w8 + 14 * MB);       // 2 MB [1024][1024]
    float*          bqkv  = (float*)(w8 + 16 * MB);                // 12 KB
    unsigned short* QKV   = (unsigned short*)(w8 + 17 * MB);       // 24 MB [4096][3072] (V region unused)
    unsigned short* Vt    = (unsigned short*)(w8 + 41 * MB);       // 8 MB [2][16][64][2048]
    unsigned short* Aout  = (unsigned short*)(w8 + 49 * MB);       // 8 MB [4096][1024]

    prep_kernel<<<3073, 256, 0, stream>>>(x, Wq, Wk, Wv, Wo, bq, bk, bv,
                                          xb, Wqkvt, Wot, bqkv);
    gemm_mfma_kernel<<<dim3(24, 32), 256, 0, stream>>>(xb, Wqkvt, bqkv, QKV, Vt,
                                                       3072, 1024, 1024);
    attn_mfma_kernel<<<1024, 256, 0, stream>>>(QKV, Vt, Aout);
    gemm_mfma_n64_kernel<<<dim3(16, 32), 256, 0, stream>>>(Aout, Wot, bo, out,
                                                           1024, 1024);
}

// Round 7
// 227.536 us; speedup vs baseline: 1.6043x; 1.2494x over previous
//
#include <hip/hip_runtime.h>
#include <hip/hip_bf16.h>
#include <math.h>

#define D_MODEL 1024
#define N_HEADS 16
#define HD 64
#define BB 2
#define TT 2048
#define MROWS (BB*TT)   // 4096

typedef __attribute__((ext_vector_type(8))) short short8;
typedef __attribute__((ext_vector_type(4))) float f32x4;

static __device__ __forceinline__ void gload16(const void* g, void* l) {
    __builtin_amdgcn_global_load_lds(
        (const __attribute__((address_space(1))) void*)g,
        (__attribute__((address_space(3))) void*)l, 16, 0, 0);
}

static __device__ __forceinline__ unsigned short f2bf(float f) {
    union { float f; unsigned u; } x; x.f = f;
    unsigned r = (x.u + 0x7fffu + ((x.u >> 16) & 1u)) >> 16;
    return (unsigned short)r;
}

// pack two f32 -> bf16x2 (round-half-up) in one v_perm
static __device__ __forceinline__ unsigned pack_bf16x2(float lo, float hi) {
    union { float f; unsigned u; } a, b; a.f = lo; b.f = hi;
    return __builtin_amdgcn_perm(b.u + 0x8000u, a.u + 0x8000u, 0x07060302u);
}

// ---------------------------------------------------------------------------
// Fused prep: blocks [0,1024) pack 4 weights (bf16, transposed);
// [1024,3072) cast x to bf16; block 3072 packs the qkv bias.
// ---------------------------------------------------------------------------
__global__ __launch_bounds__(256) void prep_kernel(
    const float* __restrict__ x,
    const float* __restrict__ Wq, const float* __restrict__ Wk,
    const float* __restrict__ Wv, const float* __restrict__ Wo,
    const float* __restrict__ bq, const float* __restrict__ bk,
    const float* __restrict__ bv,
    unsigned short* __restrict__ xb, unsigned short* __restrict__ Wqkvt,
    unsigned short* __restrict__ Wot, float* __restrict__ bqkv)
{
    __shared__ float Ts[64][65];
    const int bx = blockIdx.x, tid = threadIdx.x;
    if (bx < 1024) {
        const int z = bx >> 8, rem = bx & 255;
        const float* W = (z == 0) ? Wq : (z == 1) ? Wk : (z == 2) ? Wv : Wo;
        unsigned short* Wt = (z < 3) ? (Wqkvt + (size_t)z * 1024 * 1024) : Wot;
        const int n0 = (rem & 15) * 64, k0 = (rem >> 4) * 64;
#pragma unroll
        for (int i = 0; i < 16; ++i) {
            int lin = i * 256 + tid;
            int kl = lin >> 6, nl = lin & 63;
            Ts[nl][kl] = W[(size_t)(k0 + kl) * 1024 + n0 + nl];
        }
        __syncthreads();
#pragma unroll
        for (int i = 0; i < 16; ++i) {
            int lin = i * 256 + tid;
            int nl = lin >> 6, kl = lin & 63;
            Wt[(size_t)(n0 + nl) * 1024 + k0 + kl] = f2bf(Ts[nl][kl]);
        }
    } else if (bx < 3072) {
        int i = ((bx - 1024) * 256 + tid) * 8;
        float4 a = *(const float4*)(x + i);
        float4 b = *(const float4*)(x + i + 4);
        short8 o;
        o[0] = f2bf(a.x); o[1] = f2bf(a.y); o[2] = f2bf(a.z); o[3] = f2bf(a.w);
        o[4] = f2bf(b.x); o[5] = f2bf(b.y); o[6] = f2bf(b.z); o[7] = f2bf(b.w);
        *(short8*)(xb + i) = o;
    } else {
#pragma unroll
        for (int j = 0; j < 12; ++j) {
            int i = j * 256 + tid;
            float v = (i < 1024) ? bq[i] : ((i < 2048) ? bk[i - 1024] : bv[i - 2048]);
            bqkv[i] = v;
        }
    }
}

// ---------------------------------------------------------------------------
// MFMA GEMM (QKV): C[M][N] = A @ Bt^T + bias. 128x128 tile, BK=32, 4 waves.
// cols < qcols scaled by 0.125*log2(e) (softmax fold, exp2 domain).
// Block-cols >= 2048 are the V projection: written transposed to Vt[b][h][d][t].
// ---------------------------------------------------------------------------
#define QSCALE 0.18033688f   // 0.125 * log2(e)

__global__ __launch_bounds__(256) void gemm_mfma_kernel(
    const unsigned short* __restrict__ A, const unsigned short* __restrict__ Bt,
    const float* __restrict__ bias, unsigned short* __restrict__ Cout,
    unsigned short* __restrict__ Vt, int N, int K, int qcols)
{
    __shared__ __align__(16) unsigned short As[128 * 32];
    __shared__ __align__(16) unsigned short Bs[128 * 32];

    const int tid  = threadIdx.x;
    const int lane = tid & 63;
    const int ln   = lane & 15;
    const int qd   = lane >> 4;
    const int w    = tid >> 6;
    const int wm   = w >> 1, wn = w & 1;

    const int lin  = blockIdx.y * gridDim.x + blockIdx.x;
    const int xcd  = lin & 7;
    const int slot = lin >> 3;
    const int sxw  = gridDim.x >> 1;
    const int syw  = ((gridDim.x * gridDim.y) >> 3) / sxw;
    const int sx   = slot % sxw, sy = slot / sxw;
    const int row0 = ((xcd >> 1) * syw + sy) * 128;
    const int col0 = ((xcd & 1) * sxw + sx) * 128;

    f32x4 acc[4][4];
#pragma unroll
    for (int mi = 0; mi < 4; ++mi)
#pragma unroll
        for (int ni = 0; ni < 4; ++ni)
            acc[mi][ni] = (f32x4){0.f, 0.f, 0.f, 0.f};

    const int s0 = tid, s1 = tid + 256;
    const int rA0 = s0 >> 2, cA0 = (s0 & 3) ^ ((rA0 >> 1) & 3);
    const int rA1 = s1 >> 2, cA1 = (s1 & 3) ^ ((rA1 >> 1) & 3);
    const unsigned short* Ag0 = A + (size_t)(row0 + rA0) * K + cA0 * 8;
    const unsigned short* Ag1 = A + (size_t)(row0 + rA1) * K + cA1 * 8;
    const unsigned short* Bg0 = Bt + (size_t)(col0 + rA0) * K + cA0 * 8;
    const unsigned short* Bg1 = Bt + (size_t)(col0 + rA1) * K + cA1 * 8;
    unsigned short* AsL0 = As + s0 * 8;
    unsigned short* AsL1 = As + s1 * 8;
    unsigned short* BsL0 = Bs + s0 * 8;
    unsigned short* BsL1 = Bs + s1 * 8;

    for (int kb = 0; kb < K; kb += 32) {
        if (kb) __syncthreads();
        gload16(Ag0 + kb, AsL0);
        gload16(Ag1 + kb, AsL1);
        gload16(Bg0 + kb, BsL0);
        gload16(Bg1 + kb, BsL1);
        __builtin_amdgcn_s_waitcnt(0);
        __syncthreads();

        short8 af[4], bf[4];
#pragma unroll
        for (int i = 0; i < 4; ++i) {
            int ra = wm * 64 + i * 16 + ln;
            int pa = ra * 4 + (qd ^ ((ra >> 1) & 3));
            af[i] = *(const short8*)(As + pa * 8);
            int rb = wn * 64 + i * 16 + ln;
            int pb = rb * 4 + (qd ^ ((rb >> 1) & 3));
            bf[i] = *(const short8*)(Bs + pb * 8);
        }
#pragma unroll
        for (int mi = 0; mi < 4; ++mi)
#pragma unroll
            for (int ni = 0; ni < 4; ++ni)
                acc[mi][ni] = __builtin_amdgcn_mfma_f32_16x16x32_bf16(
                    af[mi], bf[ni], acc[mi][ni], 0, 0, 0);
    }

    float bv[4];
#pragma unroll
    for (int ni = 0; ni < 4; ++ni)
        bv[ni] = bias[col0 + wn * 64 + ni * 16 + ln];

    if (col0 >= 2048) {
        const int h = ((col0 - 2048) >> 6) + wn;
#pragma unroll
        for (int mi = 0; mi < 4; ++mi) {
            int row = row0 + wm * 64 + mi * 16 + qd * 4;
            int b = row >> 11, t = row & 2047;
#pragma unroll
            for (int ni = 0; ni < 4; ++ni) {
                int d = ni * 16 + ln;
                float v0 = acc[mi][ni][0] + bv[ni];
                float v1 = acc[mi][ni][1] + bv[ni];
                float v2 = acc[mi][ni][2] + bv[ni];
                float v3 = acc[mi][ni][3] + bv[ni];
                unsigned u0 = pack_bf16x2(v0, v1);
                unsigned u1 = pack_bf16x2(v2, v3);
                *(uint2*)(Vt + (size_t)((b * 16 + h) * 64 + d) * TT + t) =
                    make_uint2(u0, u1);
            }
        }
    } else {
        float scl[4];
#pragma unroll
        for (int ni = 0; ni < 4; ++ni)
            scl[ni] = (col0 + wn * 64 + ni * 16 < qcols) ? QSCALE : 1.0f;
#pragma unroll
        for (int mi = 0; mi < 4; ++mi)
#pragma unroll
            for (int ni = 0; ni < 4; ++ni)
#pragma unroll
                for (int r = 0; r < 4; ++r) {
                    float v = (acc[mi][ni][r] + bv[ni]) * scl[ni];
                    int row = row0 + wm * 64 + mi * 16 + qd * 4 + r;
                    int col = col0 + wn * 64 + ni * 16 + ln;
                    Cout[(size_t)row * N + col] = f2bf(v);
                }
    }
}

// ---------------------------------------------------------------------------
// MFMA GEMM (output proj): 128x64 tile -> 512 blocks (2/CU). fp32 out.
// ---------------------------------------------------------------------------
__global__ __launch_bounds__(256) void gemm_mfma_n64_kernel(
    const unsigned short* __restrict__ A, const unsigned short* __restrict__ Bt,
    const float* __restrict__ bias, float* __restrict__ Cout, int N, int K)
{
    __shared__ __align__(16) unsigned short As[128 * 32];
    __shared__ __align__(16) unsigned short Bs[64 * 32];

    const int tid  = threadIdx.x;
    const int lane = tid & 63;
    const int ln   = lane & 15;
    const int qd   = lane >> 4;
    const int w    = tid >> 6;

    const int lin  = blockIdx.y * gridDim.x + blockIdx.x;
    const int xcd  = lin & 7;
    const int slot = lin >> 3;
    const int sxw  = gridDim.x >> 1;
    const int syw  = ((gridDim.x * gridDim.y) >> 3) / sxw;
    const int sx   = slot % sxw, sy = slot / sxw;
    const int row0 = ((xcd >> 1) * syw + sy) * 128;
    const int col0 = ((xcd & 1) * sxw + sx) * 64;

    f32x4 acc[2][4];
#pragma unroll
    for (int mi = 0; mi < 2; ++mi)
#pragma unroll
        for (int ni = 0; ni < 4; ++ni)
            acc[mi][ni] = (f32x4){0.f, 0.f, 0.f, 0.f};

    const int s0 = tid, s1 = tid + 256;
    const int rA0 = s0 >> 2, cA0 = (s0 & 3) ^ ((rA0 >> 1) & 3);
    const int rA1 = s1 >> 2, cA1 = (s1 & 3) ^ ((rA1 >> 1) & 3);
    const unsigned short* Ag0 = A + (size_t)(row0 + rA0) * K + cA0 * 8;
    const unsigned short* Ag1 = A + (size_t)(row0 + rA1) * K + cA1 * 8;
    const unsigned short* Bg0 = Bt + (size_t)(col0 + rA0) * K + cA0 * 8;
    unsigned short* AsL0 = As + s0 * 8;
    unsigned short* AsL1 = As + s1 * 8;
    unsigned short* BsL0 = Bs + s0 * 8;

    for (int kb = 0; kb < K; kb += 32) {
        if (kb) __syncthreads();
        gload16(Ag0 + kb, AsL0);
        gload16(Ag1 + kb, AsL1);
        gload16(Bg0 + kb, BsL0);
        __builtin_amdgcn_s_waitcnt(0);
        __syncthreads();

        short8 af[2], bf[4];
#pragma unroll
        for (int i = 0; i < 2; ++i) {
            int ra = w * 32 + i * 16 + ln;
            int pa = ra * 4 + (qd ^ ((ra >> 1) & 3));
            af[i] = *(const short8*)(As + pa * 8);
        }
#pragma unroll
        for (int i = 0; i < 4; ++i) {
            int rb = i * 16 + ln;
            int pb = rb * 4 + (qd ^ ((rb >> 1) & 3));
            bf[i] = *(const short8*)(Bs + pb * 8);
        }
#pragma unroll
        for (int mi = 0; mi < 2; ++mi)
#pragma unroll
            for (int ni = 0; ni < 4; ++ni)
                acc[mi][ni] = __builtin_amdgcn_mfma_f32_16x16x32_bf16(
                    af[mi], bf[ni], acc[mi][ni], 0, 0, 0);
    }

    float bv[4];
#pragma unroll
    for (int ni = 0; ni < 4; ++ni)
        bv[ni] = bias[col0 + ni * 16 + ln];

#pragma unroll
    for (int mi = 0; mi < 2; ++mi)
#pragma unroll
        for (int ni = 0; ni < 4; ++ni)
#pragma unroll
            for (int r = 0; r < 4; ++r) {
                int row = row0 + w * 32 + mi * 16 + qd * 4 + r;
                int col = col0 + ni * 16 + ln;
                Cout[(size_t)row * N + col] = acc[mi][ni][r] + bv[ni];
            }
}

// ---------------------------------------------------------------------------
// Flash attention: one 64-row q-tile per block, 1024 blocks.
// Natural register allocation (NO min-waves bound: caps below ~190 regs spill
// catastrophically -- measured rounds 5/6: 516/291 MB scratch WRITE_SIZE).
// XCD-locality swizzle; heavy tiles first. exp2-domain softmax (scale folded
// into Q upstream). Zero barriers in K-loop.
// ---------------------------------------------------------------------------
#define PSTRIDE 136
#define LDS_TOTAL (4*64*PSTRIDE + 2048)

__global__ __launch_bounds__(256) void attn_mfma_kernel(
    const unsigned short* __restrict__ QKV,
    const unsigned short* __restrict__ Vt,
    unsigned short* __restrict__ Aout)
{
    __shared__ __align__(16) unsigned char lds[LDS_TOTAL];

    const int tid  = threadIdx.x;
    const int lane = tid & 63;
    const int ln   = lane & 15;
    const int qd   = lane >> 4;
    const int qd4  = qd * 4;
    const int w    = tid >> 6;

    // bx -> (b,h,qt): XCD = bx&7 pinned per bh; qt descending (heavy first)
    const int bx  = blockIdx.x;
    const int g   = bx >> 3;
    const int bh  = (bx & 7) + 8 * (g & 3);
    const int qt  = 31 - (g >> 2);
    const int b   = bh >> 4;
    const int h   = bh & 15;

    unsigned char* Pb   = lds + w * (64 * PSTRIDE);
    float*         Oacc = (float*)lds;
    float*         mlm  = (float*)(lds + 4 * 64 * PSTRIDE);
    float*         mll  = mlm + 256;

    const unsigned short* Kh = QKV + 1024 + h * 64;
    const unsigned short* Qh = QKV + h * 64;
    const unsigned short* Vh = Vt + (size_t)((b * 16 + h) * 64) * TT;

    short8 qa[4][2];
    {
        const unsigned short* Qb = Qh + (size_t)(b * TT + qt * 64) * 3072;
#pragma unroll
        for (int q4 = 0; q4 < 4; ++q4)
#pragma unroll
            for (int kk = 0; kk < 2; ++kk)
                qa[q4][kk] = *(const short8*)(Qb + (size_t)(q4 * 16 + ln) * 3072 + kk * 32 + qd * 8);
    }

    f32x4 O[4][4];
#pragma unroll
    for (int dt = 0; dt < 4; ++dt)
#pragma unroll
        for (int q4 = 0; q4 < 4; ++q4)
            O[dt][q4] = (f32x4){0.f, 0.f, 0.f, 0.f};
    float m_i[4] = {-1e30f, -1e30f, -1e30f, -1e30f};
    float l_i[4] = {0.f, 0.f, 0.f, 0.f};

    for (int kc = w; kc <= qt; kc += 4) {
        const unsigned short* Kc = Kh + (size_t)(b * TT + kc * 64) * 3072;
        const unsigned short* Vc = Vh + kc * 64;

        short8 kf[4][2];
#pragma unroll
        for (int kt = 0; kt < 4; ++kt)
#pragma unroll
            for (int kk = 0; kk < 2; ++kk)
                kf[kt][kk] = *(const short8*)(Kc + (size_t)(kt * 16 + ln) * 3072 + kk * 32 + qd * 8);

        f32x4 st[4][4];
#pragma unroll
        for (int kt = 0; kt < 4; ++kt)
#pragma unroll
            for (int q4 = 0; q4 < 4; ++q4) {
                f32x4 a = (f32x4){0.f, 0.f, 0.f, 0.f};
                a = __builtin_amdgcn_mfma_f32_16x16x32_bf16(kf[kt][0], qa[q4][0], a, 0, 0, 0);
                a = __builtin_amdgcn_mfma_f32_16x16x32_bf16(kf[kt][1], qa[q4][1], a, 0, 0, 0);
                st[kt][q4] = a;
            }

        if (kc == qt) {
#pragma unroll
            for (int kt = 0; kt < 4; ++kt)
#pragma unroll
                for (int q4 = 0; q4 < 4; ++q4)
#pragma unroll
                    for (int r = 0; r < 4; ++r)
                        if (kt * 16 + qd4 + r > q4 * 16 + ln)
                            st[kt][q4][r] = -1e30f;
        }

        float alpha[4];
#pragma unroll
        for (int q4 = 0; q4 < 4; ++q4) {
            float mx = st[0][q4][0];
#pragma unroll
            for (int kt = 0; kt < 4; ++kt)
#pragma unroll
                for (int r = 0; r < 4; ++r)
                    mx = fmaxf(mx, st[kt][q4][r]);
            mx = fmaxf(mx, __shfl_xor(mx, 16, 64));
            mx = fmaxf(mx, __shfl_xor(mx, 32, 64));
            float mn = fmaxf(m_i[q4], mx);
            alpha[q4] = exp2f(m_i[q4] - mn);
            m_i[q4] = mn;
        }
#pragma unroll
        for (int kt = 0; kt < 4; ++kt)
#pragma unroll
            for (int q4 = 0; q4 < 4; ++q4)
#pragma unroll
                for (int r = 0; r < 4; ++r)
                    st[kt][q4][r] = exp2f(st[kt][q4][r] - m_i[q4]);
#pragma unroll
        for (int q4 = 0; q4 < 4; ++q4) {
            float sm = 0.f;
#pragma unroll
            for (int kt = 0; kt < 4; ++kt)
#pragma unroll
                for (int r = 0; r < 4; ++r)
                    sm += st[kt][q4][r];
            sm += __shfl_xor(sm, 16, 64);
            sm += __shfl_xor(sm, 32, 64);
            l_i[q4] = l_i[q4] * alpha[q4] + sm;
        }
#pragma unroll
        for (int dt = 0; dt < 4; ++dt)
#pragma unroll
            for (int q4 = 0; q4 < 4; ++q4) {
                O[dt][q4][0] *= alpha[q4]; O[dt][q4][1] *= alpha[q4];
                O[dt][q4][2] *= alpha[q4]; O[dt][q4][3] *= alpha[q4];
            }

#pragma unroll
        for (int kt = 0; kt < 4; ++kt)
#pragma unroll
            for (int q4 = 0; q4 < 4; ++q4) {
                unsigned u0 = pack_bf16x2(st[kt][q4][0], st[kt][q4][1]);
                unsigned u1 = pack_bf16x2(st[kt][q4][2], st[kt][q4][3]);
                *(uint2*)(Pb + (q4 * 16 + ln) * PSTRIDE + kt * 32 + qd * 8) =
                    make_uint2(u0, u1);
            }

        // V fragments loaded late (shorter live range than upfront)
        short8 vf[4][2];
#pragma unroll
        for (int dt = 0; dt < 4; ++dt)
#pragma unroll
            for (int kk = 0; kk < 2; ++kk)
                vf[dt][kk] = *(const short8*)(Vc + (size_t)(dt * 16 + ln) * TT + kk * 32 + qd * 8);

#pragma unroll
        for (int kk = 0; kk < 2; ++kk)
#pragma unroll
            for (int q4 = 0; q4 < 4; ++q4) {
                union { struct { uint2 a, b; } u; short8 s; } y;
                const unsigned char* yp = Pb + (q4 * 16 + ln) * PSTRIDE + kk * 64 + qd * 16;
                y.u.a = *(const uint2*)(yp);
                y.u.b = *(const uint2*)(yp + 8);
#pragma unroll
                for (int dt = 0; dt < 4; ++dt)
                    O[dt][q4] = __builtin_amdgcn_mfma_f32_16x16x32_bf16(
                        vf[dt][kk], y.s, O[dt][q4], 0, 0, 0);
            }
    }

    if (qd == 0) {
#pragma unroll
        for (int q4 = 0; q4 < 4; ++q4) {
            mlm[w * 64 + q4 * 16 + ln] = m_i[q4];
            mll[w * 64 + q4 * 16 + ln] = l_i[q4];
        }
    }
    __syncthreads();

    float fac[4];
#pragma unroll
    for (int q4 = 0; q4 < 4; ++q4) {
        int q = q4 * 16 + ln;
        float m0 = mlm[q], m1 = mlm[64 + q], m2 = mlm[128 + q], m3 = mlm[192 + q];
        float M = fmaxf(fmaxf(m0, m1), fmaxf(m2, m3));
        float f0 = exp2f(m0 - M), f1 = exp2f(m1 - M);
        float f2 = exp2f(m2 - M), f3 = exp2f(m3 - M);
        float L = f0 * mll[q] + f1 * mll[64 + q] + f2 * mll[128 + q] + f3 * mll[192 + q];
        float myf = (w == 0) ? f0 : (w == 1) ? f1 : (w == 2) ? f2 : f3;
        fac[q4] = myf / L;
    }
#pragma unroll
    for (int dt = 0; dt < 4; ++dt)
#pragma unroll
        for (int q4 = 0; q4 < 4; ++q4) {
            O[dt][q4][0] *= fac[q4]; O[dt][q4][1] *= fac[q4];
            O[dt][q4][2] *= fac[q4]; O[dt][q4][3] *= fac[q4];
        }

    for (int wv = 0; wv < 4; ++wv) {
        if (w == wv) {
#pragma unroll
            for (int dt = 0; dt < 4; ++dt)
#pragma unroll
                for (int q4 = 0; q4 < 4; ++q4) {
                    float* pp = Oacc + (q4 * 16 + ln) * 68 + dt * 16 + qd4;
                    if (wv == 0) {
                        *(f32x4*)pp = O[dt][q4];
                    } else {
                        f32x4 t = *(const f32x4*)pp;
                        t += O[dt][q4];
                        *(f32x4*)pp = t;
                    }
                }
        }
        __syncthreads();
    }

    {
        int q = tid >> 2, dg = tid & 3;
        const float* rowp = Oacc + q * 68 + dg * 16;
        short8 s0v, s1v;
#pragma unroll
        for (int i = 0; i < 8; ++i) {
            s0v[i] = f2bf(rowp[i]);
            s1v[i] = f2bf(rowp[8 + i]);
        }
        size_t orow = (size_t)(b * TT + qt * 64 + q) * D_MODEL + h * 64 + dg * 16;
        *(short8*)(Aout + orow) = s0v;
        *(short8*)(Aout + orow + 8) = s1v;
    }
}

// ---------------------------------------------------------------------------
extern "C" void kernel_launch(void* const* d_in, const int* in_sizes, int n_in,
                              void* d_out, int out_size, void* d_ws, size_t ws_size,
                              hipStream_t stream) {
    const float* x  = (const float*)d_in[0];
    const float* Wq = (const float*)d_in[2];
    const float* bq = (const float*)d_in[3];
    const float* Wk = (const float*)d_in[4];
    const float* bk = (const float*)d_in[5];
    const float* Wv = (const float*)d_in[6];
    const float* bv = (const float*)d_in[7];
    const float* Wo = (const float*)d_in[8];
    const float* bo = (const float*)d_in[9];
    float* out = (float*)d_out;

    uint8_t* w8 = (uint8_t*)d_ws;
    const size_t MB = 1024 * 1024;
    unsigned short* xb    = (unsigned short*)(w8);                 // 8 MB [4096][1024]
    unsigned short* Wqkvt = (unsigned short*)(w8 + 8 * MB);        // 6 MB [3072][1024]
    unsigned short* Wot   = (unsigned short*)(w8 + 14 * MB);       // 2 MB [1024][1024]
    float*          bqkv  = (float*)(w8 + 16 * MB);                // 12 KB
    unsigned short* QKV   = (unsigned short*)(w8 + 17 * MB);       // 24 MB [4096][3072] (V region unused)
    unsigned short* Vt    = (unsigned short*)(w8 + 41 * MB);       // 8 MB [2][16][64][2048]
    unsigned short* Aout  = (unsigned short*)(w8 + 49 * MB);       // 8 MB [4096][1024]

    prep_kernel<<<3073, 256, 0, stream>>>(x, Wq, Wk, Wv, Wo, bq, bk, bv,
                                          xb, Wqkvt, Wot, bqkv);
    gemm_mfma_kernel<<<dim3(24, 32), 256, 0, stream>>>(xb, Wqkvt, bqkv, QKV, Vt,
                                                       3072, 1024, 1024);
    attn_mfma_kernel<<<1024, 256, 0, stream>>>(QKV, Vt, Aout);
    gemm_mfma_n64_kernel<<<dim3(16, 32), 256, 0, stream>>>(Aout, Wot, bo, out,
                                                           1024, 1024);
}

// Round 8
// 226.585 us; speedup vs baseline: 1.6110x; 1.0042x over previous
//
#include <hip/hip_runtime.h>
#include <hip/hip_bf16.h>
#include <math.h>

#define D_MODEL 1024
#define N_HEADS 16
#define HD 64
#define BB 2
#define TT 2048
#define MROWS (BB*TT)   // 4096

typedef __attribute__((ext_vector_type(8))) short short8;
typedef __attribute__((ext_vector_type(4))) float f32x4;

static __device__ __forceinline__ void gload16(const void* g, void* l) {
    __builtin_amdgcn_global_load_lds(
        (const __attribute__((address_space(1))) void*)g,
        (__attribute__((address_space(3))) void*)l, 16, 0, 0);
}

static __device__ __forceinline__ unsigned short f2bf(float f) {
    union { float f; unsigned u; } x; x.f = f;
    unsigned r = (x.u + 0x7fffu + ((x.u >> 16) & 1u)) >> 16;
    return (unsigned short)r;
}

// pack two f32 -> bf16x2 (round-half-up) in one v_perm
static __device__ __forceinline__ unsigned pack_bf16x2(float lo, float hi) {
    union { float f; unsigned u; } a, b; a.f = lo; b.f = hi;
    return __builtin_amdgcn_perm(b.u + 0x8000u, a.u + 0x8000u, 0x07060302u);
}

// ---------------------------------------------------------------------------
// Fused prep: blocks [0,1024) pack 4 weights (bf16, transposed);
// [1024,3072) cast x to bf16; block 3072 packs the qkv bias.
// ---------------------------------------------------------------------------
__global__ __launch_bounds__(256) void prep_kernel(
    const float* __restrict__ x,
    const float* __restrict__ Wq, const float* __restrict__ Wk,
    const float* __restrict__ Wv, const float* __restrict__ Wo,
    const float* __restrict__ bq, const float* __restrict__ bk,
    const float* __restrict__ bv,
    unsigned short* __restrict__ xb, unsigned short* __restrict__ Wqkvt,
    unsigned short* __restrict__ Wot, float* __restrict__ bqkv)
{
    __shared__ float Ts[64][65];
    const int bx = blockIdx.x, tid = threadIdx.x;
    if (bx < 1024) {
        const int z = bx >> 8, rem = bx & 255;
        const float* W = (z == 0) ? Wq : (z == 1) ? Wk : (z == 2) ? Wv : Wo;
        unsigned short* Wt = (z < 3) ? (Wqkvt + (size_t)z * 1024 * 1024) : Wot;
        const int n0 = (rem & 15) * 64, k0 = (rem >> 4) * 64;
#pragma unroll
        for (int i = 0; i < 16; ++i) {
            int lin = i * 256 + tid;
            int kl = lin >> 6, nl = lin & 63;
            Ts[nl][kl] = W[(size_t)(k0 + kl) * 1024 + n0 + nl];
        }
        __syncthreads();
#pragma unroll
        for (int i = 0; i < 16; ++i) {
            int lin = i * 256 + tid;
            int nl = lin >> 6, kl = lin & 63;
            Wt[(size_t)(n0 + nl) * 1024 + k0 + kl] = f2bf(Ts[nl][kl]);
        }
    } else if (bx < 3072) {
        int i = ((bx - 1024) * 256 + tid) * 8;
        float4 a = *(const float4*)(x + i);
        float4 b = *(const float4*)(x + i + 4);
        short8 o;
        o[0] = f2bf(a.x); o[1] = f2bf(a.y); o[2] = f2bf(a.z); o[3] = f2bf(a.w);
        o[4] = f2bf(b.x); o[5] = f2bf(b.y); o[6] = f2bf(b.z); o[7] = f2bf(b.w);
        *(short8*)(xb + i) = o;
    } else {
#pragma unroll
        for (int j = 0; j < 12; ++j) {
            int i = j * 256 + tid;
            float v = (i < 1024) ? bq[i] : ((i < 2048) ? bk[i - 1024] : bv[i - 2048]);
            bqkv[i] = v;
        }
    }
}

// ---------------------------------------------------------------------------
// MFMA GEMM (QKV): C[M][N] = A @ Bt^T + bias. 128x128 tile, BK=32, 4 waves.
// cols < qcols scaled by 0.125*log2(e) (softmax fold, exp2 domain).
// Block-cols >= 2048 are the V projection: written transposed to Vt[b][h][d][t].
// ---------------------------------------------------------------------------
#define QSCALE 0.18033688f   // 0.125 * log2(e)

__global__ __launch_bounds__(256) void gemm_mfma_kernel(
    const unsigned short* __restrict__ A, const unsigned short* __restrict__ Bt,
    const float* __restrict__ bias, unsigned short* __restrict__ Cout,
    unsigned short* __restrict__ Vt, int N, int K, int qcols)
{
    __shared__ __align__(16) unsigned short As[128 * 32];
    __shared__ __align__(16) unsigned short Bs[128 * 32];

    const int tid  = threadIdx.x;
    const int lane = tid & 63;
    const int ln   = lane & 15;
    const int qd   = lane >> 4;
    const int w    = tid >> 6;
    const int wm   = w >> 1, wn = w & 1;

    const int lin  = blockIdx.y * gridDim.x + blockIdx.x;
    const int xcd  = lin & 7;
    const int slot = lin >> 3;
    const int sxw  = gridDim.x >> 1;
    const int syw  = ((gridDim.x * gridDim.y) >> 3) / sxw;
    const int sx   = slot % sxw, sy = slot / sxw;
    const int row0 = ((xcd >> 1) * syw + sy) * 128;
    const int col0 = ((xcd & 1) * sxw + sx) * 128;

    f32x4 acc[4][4];
#pragma unroll
    for (int mi = 0; mi < 4; ++mi)
#pragma unroll
        for (int ni = 0; ni < 4; ++ni)
            acc[mi][ni] = (f32x4){0.f, 0.f, 0.f, 0.f};

    const int s0 = tid, s1 = tid + 256;
    const int rA0 = s0 >> 2, cA0 = (s0 & 3) ^ ((rA0 >> 1) & 3);
    const int rA1 = s1 >> 2, cA1 = (s1 & 3) ^ ((rA1 >> 1) & 3);
    const unsigned short* Ag0 = A + (size_t)(row0 + rA0) * K + cA0 * 8;
    const unsigned short* Ag1 = A + (size_t)(row0 + rA1) * K + cA1 * 8;
    const unsigned short* Bg0 = Bt + (size_t)(col0 + rA0) * K + cA0 * 8;
    const unsigned short* Bg1 = Bt + (size_t)(col0 + rA1) * K + cA1 * 8;
    unsigned short* AsL0 = As + s0 * 8;
    unsigned short* AsL1 = As + s1 * 8;
    unsigned short* BsL0 = Bs + s0 * 8;
    unsigned short* BsL1 = Bs + s1 * 8;

    for (int kb = 0; kb < K; kb += 32) {
        if (kb) __syncthreads();
        gload16(Ag0 + kb, AsL0);
        gload16(Ag1 + kb, AsL1);
        gload16(Bg0 + kb, BsL0);
        gload16(Bg1 + kb, BsL1);
        __builtin_amdgcn_s_waitcnt(0);
        __syncthreads();

        short8 af[4], bf[4];
#pragma unroll
        for (int i = 0; i < 4; ++i) {
            int ra = wm * 64 + i * 16 + ln;
            int pa = ra * 4 + (qd ^ ((ra >> 1) & 3));
            af[i] = *(const short8*)(As + pa * 8);
            int rb = wn * 64 + i * 16 + ln;
            int pb = rb * 4 + (qd ^ ((rb >> 1) & 3));
            bf[i] = *(const short8*)(Bs + pb * 8);
        }
#pragma unroll
        for (int mi = 0; mi < 4; ++mi)
#pragma unroll
            for (int ni = 0; ni < 4; ++ni)
                acc[mi][ni] = __builtin_amdgcn_mfma_f32_16x16x32_bf16(
                    af[mi], bf[ni], acc[mi][ni], 0, 0, 0);
    }

    float bv[4];
#pragma unroll
    for (int ni = 0; ni < 4; ++ni)
        bv[ni] = bias[col0 + wn * 64 + ni * 16 + ln];

    if (col0 >= 2048) {
        const int h = ((col0 - 2048) >> 6) + wn;
#pragma unroll
        for (int mi = 0; mi < 4; ++mi) {
            int row = row0 + wm * 64 + mi * 16 + qd * 4;
            int b = row >> 11, t = row & 2047;
#pragma unroll
            for (int ni = 0; ni < 4; ++ni) {
                int d = ni * 16 + ln;
                float v0 = acc[mi][ni][0] + bv[ni];
                float v1 = acc[mi][ni][1] + bv[ni];
                float v2 = acc[mi][ni][2] + bv[ni];
                float v3 = acc[mi][ni][3] + bv[ni];
                unsigned u0 = pack_bf16x2(v0, v1);
                unsigned u1 = pack_bf16x2(v2, v3);
                *(uint2*)(Vt + (size_t)((b * 16 + h) * 64 + d) * TT + t) =
                    make_uint2(u0, u1);
            }
        }
    } else {
        float scl[4];
#pragma unroll
        for (int ni = 0; ni < 4; ++ni)
            scl[ni] = (col0 + wn * 64 + ni * 16 < qcols) ? QSCALE : 1.0f;
#pragma unroll
        for (int mi = 0; mi < 4; ++mi)
#pragma unroll
            for (int ni = 0; ni < 4; ++ni)
#pragma unroll
                for (int r = 0; r < 4; ++r) {
                    float v = (acc[mi][ni][r] + bv[ni]) * scl[ni];
                    int row = row0 + wm * 64 + mi * 16 + qd * 4 + r;
                    int col = col0 + wn * 64 + ni * 16 + ln;
                    Cout[(size_t)row * N + col] = f2bf(v);
                }
    }
}

// ---------------------------------------------------------------------------
// MFMA GEMM (output proj): 128x64 tile -> 512 blocks (2/CU). fp32 out.
// ---------------------------------------------------------------------------
__global__ __launch_bounds__(256) void gemm_mfma_n64_kernel(
    const unsigned short* __restrict__ A, const unsigned short* __restrict__ Bt,
    const float* __restrict__ bias, float* __restrict__ Cout, int N, int K)
{
    __shared__ __align__(16) unsigned short As[128 * 32];
    __shared__ __align__(16) unsigned short Bs[64 * 32];

    const int tid  = threadIdx.x;
    const int lane = tid & 63;
    const int ln   = lane & 15;
    const int qd   = lane >> 4;
    const int w    = tid >> 6;

    const int lin  = blockIdx.y * gridDim.x + blockIdx.x;
    const int xcd  = lin & 7;
    const int slot = lin >> 3;
    const int sxw  = gridDim.x >> 1;
    const int syw  = ((gridDim.x * gridDim.y) >> 3) / sxw;
    const int sx   = slot % sxw, sy = slot / sxw;
    const int row0 = ((xcd >> 1) * syw + sy) * 128;
    const int col0 = ((xcd & 1) * sxw + sx) * 64;

    f32x4 acc[2][4];
#pragma unroll
    for (int mi = 0; mi < 2; ++mi)
#pragma unroll
        for (int ni = 0; ni < 4; ++ni)
            acc[mi][ni] = (f32x4){0.f, 0.f, 0.f, 0.f};

    const int s0 = tid, s1 = tid + 256;
    const int rA0 = s0 >> 2, cA0 = (s0 & 3) ^ ((rA0 >> 1) & 3);
    const int rA1 = s1 >> 2, cA1 = (s1 & 3) ^ ((rA1 >> 1) & 3);
    const unsigned short* Ag0 = A + (size_t)(row0 + rA0) * K + cA0 * 8;
    const unsigned short* Ag1 = A + (size_t)(row0 + rA1) * K + cA1 * 8;
    const unsigned short* Bg0 = Bt + (size_t)(col0 + rA0) * K + cA0 * 8;
    unsigned short* AsL0 = As + s0 * 8;
    unsigned short* AsL1 = As + s1 * 8;
    unsigned short* BsL0 = Bs + s0 * 8;

    for (int kb = 0; kb < K; kb += 32) {
        if (kb) __syncthreads();
        gload16(Ag0 + kb, AsL0);
        gload16(Ag1 + kb, AsL1);
        gload16(Bg0 + kb, BsL0);
        __builtin_amdgcn_s_waitcnt(0);
        __syncthreads();

        short8 af[2], bf[4];
#pragma unroll
        for (int i = 0; i < 2; ++i) {
            int ra = w * 32 + i * 16 + ln;
            int pa = ra * 4 + (qd ^ ((ra >> 1) & 3));
            af[i] = *(const short8*)(As + pa * 8);
        }
#pragma unroll
        for (int i = 0; i < 4; ++i) {
            int rb = i * 16 + ln;
            int pb = rb * 4 + (qd ^ ((rb >> 1) & 3));
            bf[i] = *(const short8*)(Bs + pb * 8);
        }
#pragma unroll
        for (int mi = 0; mi < 2; ++mi)
#pragma unroll
            for (int ni = 0; ni < 4; ++ni)
                acc[mi][ni] = __builtin_amdgcn_mfma_f32_16x16x32_bf16(
                    af[mi], bf[ni], acc[mi][ni], 0, 0, 0);
    }

    float bv[4];
#pragma unroll
    for (int ni = 0; ni < 4; ++ni)
        bv[ni] = bias[col0 + ni * 16 + ln];

#pragma unroll
    for (int mi = 0; mi < 2; ++mi)
#pragma unroll
        for (int ni = 0; ni < 4; ++ni)
#pragma unroll
            for (int r = 0; r < 4; ++r) {
                int row = row0 + w * 32 + mi * 16 + qd * 4 + r;
                int col = col0 + ni * 16 + ln;
                Cout[(size_t)row * N + col] = acc[mi][ni][r] + bv[ni];
            }
}

// ---------------------------------------------------------------------------
// Flash attention: round-4 body (2-tile pair per block, balanced 33 chunks,
// V loaded EARLY, natural VGPR ~124) + XCD-pinned bh mapping (round-7 proven:
// FETCH 12 MB) + exp2-domain softmax. 512 blocks = 2/CU, all resident.
// NO min-waves launch bound (caps below natural footprint spill -- r5/r6).
// ---------------------------------------------------------------------------
#define PSTRIDE 136
#define LDS_TOTAL (4*64*PSTRIDE + 2048)

__global__ __launch_bounds__(256) void attn_mfma_kernel(
    const unsigned short* __restrict__ QKV,
    const unsigned short* __restrict__ Vt,
    unsigned short* __restrict__ Aout)
{
    __shared__ __align__(16) unsigned char lds[LDS_TOTAL];

    const int tid  = threadIdx.x;
    const int lane = tid & 63;
    const int ln   = lane & 15;
    const int qd   = lane >> 4;
    const int qd4  = qd * 4;
    const int w    = tid >> 6;

    // 512 blocks: XCD = bx&7 pinned per bh (4 bh per XCD), p = tile pair idx
    const int bx  = blockIdx.x;
    const int bh  = (bx & 7) + 8 * ((bx >> 3) & 3);
    const int p   = bx >> 5;                 // 0..15
    const int b   = bh >> 4;
    const int h   = bh & 15;

    unsigned char* Pb   = lds + w * (64 * PSTRIDE);
    float*         Oacc = (float*)lds;
    float*         mlm  = (float*)(lds + 4 * 64 * PSTRIDE);
    float*         mll  = mlm + 256;

    const unsigned short* Kh = QKV + 1024 + h * 64;
    const unsigned short* Qh = QKV + h * 64;
    const unsigned short* Vh = Vt + (size_t)((b * 16 + h) * 64) * TT;

    for (int ti = 0; ti < 2; ++ti) {
        const int qt = ti ? p : (31 - p);
        __syncthreads();   // P/Oacc region safe to reuse

        short8 qa[4][2];
        {
            const unsigned short* Qb = Qh + (size_t)(b * TT + qt * 64) * 3072;
#pragma unroll
            for (int q4 = 0; q4 < 4; ++q4)
#pragma unroll
                for (int kk = 0; kk < 2; ++kk)
                    qa[q4][kk] = *(const short8*)(Qb + (size_t)(q4 * 16 + ln) * 3072 + kk * 32 + qd * 8);
        }

        f32x4 O[4][4];
#pragma unroll
        for (int dt = 0; dt < 4; ++dt)
#pragma unroll
            for (int q4 = 0; q4 < 4; ++q4)
                O[dt][q4] = (f32x4){0.f, 0.f, 0.f, 0.f};
        float m_i[4] = {-1e30f, -1e30f, -1e30f, -1e30f};
        float l_i[4] = {0.f, 0.f, 0.f, 0.f};

        for (int kc = w; kc <= qt; kc += 4) {
            const unsigned short* Kc = Kh + (size_t)(b * TT + kc * 64) * 3072;
            const unsigned short* Vc = Vh + kc * 64;

            short8 kf[4][2], vf[4][2];
#pragma unroll
            for (int kt = 0; kt < 4; ++kt)
#pragma unroll
                for (int kk = 0; kk < 2; ++kk)
                    kf[kt][kk] = *(const short8*)(Kc + (size_t)(kt * 16 + ln) * 3072 + kk * 32 + qd * 8);
#pragma unroll
            for (int dt = 0; dt < 4; ++dt)
#pragma unroll
                for (int kk = 0; kk < 2; ++kk)
                    vf[dt][kk] = *(const short8*)(Vc + (size_t)(dt * 16 + ln) * TT + kk * 32 + qd * 8);

            f32x4 st[4][4];
#pragma unroll
            for (int kt = 0; kt < 4; ++kt)
#pragma unroll
                for (int q4 = 0; q4 < 4; ++q4) {
                    f32x4 a = (f32x4){0.f, 0.f, 0.f, 0.f};
                    a = __builtin_amdgcn_mfma_f32_16x16x32_bf16(kf[kt][0], qa[q4][0], a, 0, 0, 0);
                    a = __builtin_amdgcn_mfma_f32_16x16x32_bf16(kf[kt][1], qa[q4][1], a, 0, 0, 0);
                    st[kt][q4] = a;
                }

            if (kc == qt) {
#pragma unroll
                for (int kt = 0; kt < 4; ++kt)
#pragma unroll
                    for (int q4 = 0; q4 < 4; ++q4)
#pragma unroll
                        for (int r = 0; r < 4; ++r)
                            if (kt * 16 + qd4 + r > q4 * 16 + ln)
                                st[kt][q4][r] = -1e30f;
            }

            float alpha[4];
#pragma unroll
            for (int q4 = 0; q4 < 4; ++q4) {
                float mx = st[0][q4][0];
#pragma unroll
                for (int kt = 0; kt < 4; ++kt)
#pragma unroll
                    for (int r = 0; r < 4; ++r)
                        mx = fmaxf(mx, st[kt][q4][r]);
                mx = fmaxf(mx, __shfl_xor(mx, 16, 64));
                mx = fmaxf(mx, __shfl_xor(mx, 32, 64));
                float mn = fmaxf(m_i[q4], mx);
                alpha[q4] = exp2f(m_i[q4] - mn);
                m_i[q4] = mn;
            }
#pragma unroll
            for (int kt = 0; kt < 4; ++kt)
#pragma unroll
                for (int q4 = 0; q4 < 4; ++q4)
#pragma unroll
                    for (int r = 0; r < 4; ++r)
                        st[kt][q4][r] = exp2f(st[kt][q4][r] - m_i[q4]);
#pragma unroll
            for (int q4 = 0; q4 < 4; ++q4) {
                float sm = 0.f;
#pragma unroll
                for (int kt = 0; kt < 4; ++kt)
#pragma unroll
                    for (int r = 0; r < 4; ++r)
                        sm += st[kt][q4][r];
                sm += __shfl_xor(sm, 16, 64);
                sm += __shfl_xor(sm, 32, 64);
                l_i[q4] = l_i[q4] * alpha[q4] + sm;
            }
#pragma unroll
            for (int dt = 0; dt < 4; ++dt)
#pragma unroll
                for (int q4 = 0; q4 < 4; ++q4) {
                    O[dt][q4][0] *= alpha[q4]; O[dt][q4][1] *= alpha[q4];
                    O[dt][q4][2] *= alpha[q4]; O[dt][q4][3] *= alpha[q4];
                }

#pragma unroll
            for (int kt = 0; kt < 4; ++kt)
#pragma unroll
                for (int q4 = 0; q4 < 4; ++q4) {
                    unsigned u0 = pack_bf16x2(st[kt][q4][0], st[kt][q4][1]);
                    unsigned u1 = pack_bf16x2(st[kt][q4][2], st[kt][q4][3]);
                    *(uint2*)(Pb + (q4 * 16 + ln) * PSTRIDE + kt * 32 + qd * 8) =
                        make_uint2(u0, u1);
                }

#pragma unroll
            for (int kk = 0; kk < 2; ++kk)
#pragma unroll
                for (int q4 = 0; q4 < 4; ++q4) {
                    union { struct { uint2 a, b; } u; short8 s; } y;
                    const unsigned char* yp = Pb + (q4 * 16 + ln) * PSTRIDE + kk * 64 + qd * 16;
                    y.u.a = *(const uint2*)(yp);
                    y.u.b = *(const uint2*)(yp + 8);
#pragma unroll
                    for (int dt = 0; dt < 4; ++dt)
                        O[dt][q4] = __builtin_amdgcn_mfma_f32_16x16x32_bf16(
                            vf[dt][kk], y.s, O[dt][q4], 0, 0, 0);
                }
        }

        if (qd == 0) {
#pragma unroll
            for (int q4 = 0; q4 < 4; ++q4) {
                mlm[w * 64 + q4 * 16 + ln] = m_i[q4];
                mll[w * 64 + q4 * 16 + ln] = l_i[q4];
            }
        }
        __syncthreads();

        float fac[4];
#pragma unroll
        for (int q4 = 0; q4 < 4; ++q4) {
            int q = q4 * 16 + ln;
            float m0 = mlm[q], m1 = mlm[64 + q], m2 = mlm[128 + q], m3 = mlm[192 + q];
            float M = fmaxf(fmaxf(m0, m1), fmaxf(m2, m3));
            float f0 = exp2f(m0 - M), f1 = exp2f(m1 - M);
            float f2 = exp2f(m2 - M), f3 = exp2f(m3 - M);
            float L = f0 * mll[q] + f1 * mll[64 + q] + f2 * mll[128 + q] + f3 * mll[192 + q];
            float myf = (w == 0) ? f0 : (w == 1) ? f1 : (w == 2) ? f2 : f3;
            fac[q4] = myf / L;
        }
#pragma unroll
        for (int dt = 0; dt < 4; ++dt)
#pragma unroll
            for (int q4 = 0; q4 < 4; ++q4) {
                O[dt][q4][0] *= fac[q4]; O[dt][q4][1] *= fac[q4];
                O[dt][q4][2] *= fac[q4]; O[dt][q4][3] *= fac[q4];
            }

        for (int wv = 0; wv < 4; ++wv) {
            if (w == wv) {
#pragma unroll
                for (int dt = 0; dt < 4; ++dt)
#pragma unroll
                    for (int q4 = 0; q4 < 4; ++q4) {
                        float* pp = Oacc + (q4 * 16 + ln) * 68 + dt * 16 + qd4;
                        if (wv == 0) {
                            *(f32x4*)pp = O[dt][q4];
                        } else {
                            f32x4 t = *(const f32x4*)pp;
                            t += O[dt][q4];
                            *(f32x4*)pp = t;
                        }
                    }
            }
            __syncthreads();
        }

        {
            int q = tid >> 2, dg = tid & 3;
            const float* rowp = Oacc + q * 68 + dg * 16;
            short8 s0v, s1v;
#pragma unroll
            for (int i = 0; i < 8; ++i) {
                s0v[i] = f2bf(rowp[i]);
                s1v[i] = f2bf(rowp[8 + i]);
            }
            size_t orow = (size_t)(b * TT + qt * 64 + q) * D_MODEL + h * 64 + dg * 16;
            *(short8*)(Aout + orow) = s0v;
            *(short8*)(Aout + orow + 8) = s1v;
        }
    }
}

// ---------------------------------------------------------------------------
extern "C" void kernel_launch(void* const* d_in, const int* in_sizes, int n_in,
                              void* d_out, int out_size, void* d_ws, size_t ws_size,
                              hipStream_t stream) {
    const float* x  = (const float*)d_in[0];
    const float* Wq = (const float*)d_in[2];
    const float* bq = (const float*)d_in[3];
    const float* Wk = (const float*)d_in[4];
    const float* bk = (const float*)d_in[5];
    const float* Wv = (const float*)d_in[6];
    const float* bv = (const float*)d_in[7];
    const float* Wo = (const float*)d_in[8];
    const float* bo = (const float*)d_in[9];
    float* out = (float*)d_out;

    uint8_t* w8 = (uint8_t*)d_ws;
    const size_t MB = 1024 * 1024;
    unsigned short* xb    = (unsigned short*)(w8);                 // 8 MB [4096][1024]
    unsigned short* Wqkvt = (unsigned short*)(w8 + 8 * MB);        // 6 MB [3072][1024]
    unsigned short* Wot   = (unsigned short*)(w8 + 14 * MB);       // 2 MB [1024][1024]
    float*          bqkv  = (float*)(w8 + 16 * MB);                // 12 KB
    unsigned short* QKV   = (unsigned short*)(w8 + 17 * MB);       // 24 MB [4096][3072] (V region unused)
    unsigned short* Vt    = (unsigned short*)(w8 + 41 * MB);       // 8 MB [2][16][64][2048]
    unsigned short* Aout  = (unsigned short*)(w8 + 49 * MB);       // 8 MB [4096][1024]

    prep_kernel<<<3073, 256, 0, stream>>>(x, Wq, Wk, Wv, Wo, bq, bk, bv,
                                          xb, Wqkvt, Wot, bqkv);
    gemm_mfma_kernel<<<dim3(24, 32), 256, 0, stream>>>(xb, Wqkvt, bqkv, QKV, Vt,
                                                       3072, 1024, 1024);
    attn_mfma_kernel<<<512, 256, 0, stream>>>(QKV, Vt, Aout);
    gemm_mfma_n64_kernel<<<dim3(16, 32), 256, 0, stream>>>(Aout, Wot, bo, out,
                                                           1024, 1024);
}

// Round 9
// 222.099 us; speedup vs baseline: 1.6436x; 1.0202x over previous
//
#include <hip/hip_runtime.h>
#include <hip/hip_bf16.h>
#include <math.h>

#define D_MODEL 1024
#define N_HEADS 16
#define HD 64
#define BB 2
#define TT 2048
#define MROWS (BB*TT)   // 4096

typedef __attribute__((ext_vector_type(8))) short short8;
typedef __attribute__((ext_vector_type(4))) float f32x4;

static __device__ __forceinline__ void gload16(const void* g, void* l) {
    __builtin_amdgcn_global_load_lds(
        (const __attribute__((address_space(1))) void*)g,
        (__attribute__((address_space(3))) void*)l, 16, 0, 0);
}

static __device__ __forceinline__ unsigned short f2bf(float f) {
    union { float f; unsigned u; } x; x.f = f;
    unsigned r = (x.u + 0x7fffu + ((x.u >> 16) & 1u)) >> 16;
    return (unsigned short)r;
}

// pack two f32 -> bf16x2 (round-half-up) in one v_perm
static __device__ __forceinline__ unsigned pack_bf16x2(float lo, float hi) {
    union { float f; unsigned u; } a, b; a.f = lo; b.f = hi;
    return __builtin_amdgcn_perm(b.u + 0x8000u, a.u + 0x8000u, 0x07060302u);
}

// ---------------------------------------------------------------------------
// Fused prep: blocks [0,1024) pack 4 weights (bf16, transposed);
// [1024,3072) cast x to bf16; block 3072 packs the qkv bias.
// ---------------------------------------------------------------------------
__global__ __launch_bounds__(256) void prep_kernel(
    const float* __restrict__ x,
    const float* __restrict__ Wq, const float* __restrict__ Wk,
    const float* __restrict__ Wv, const float* __restrict__ Wo,
    const float* __restrict__ bq, const float* __restrict__ bk,
    const float* __restrict__ bv,
    unsigned short* __restrict__ xb, unsigned short* __restrict__ Wqkvt,
    unsigned short* __restrict__ Wot, float* __restrict__ bqkv)
{
    __shared__ float Ts[64][65];
    const int bx = blockIdx.x, tid = threadIdx.x;
    if (bx < 1024) {
        const int z = bx >> 8, rem = bx & 255;
        const float* W = (z == 0) ? Wq : (z == 1) ? Wk : (z == 2) ? Wv : Wo;
        unsigned short* Wt = (z < 3) ? (Wqkvt + (size_t)z * 1024 * 1024) : Wot;
        const int n0 = (rem & 15) * 64, k0 = (rem >> 4) * 64;
#pragma unroll
        for (int i = 0; i < 16; ++i) {
            int lin = i * 256 + tid;
            int kl = lin >> 6, nl = lin & 63;
            Ts[nl][kl] = W[(size_t)(k0 + kl) * 1024 + n0 + nl];
        }
        __syncthreads();
#pragma unroll
        for (int i = 0; i < 16; ++i) {
            int lin = i * 256 + tid;
            int nl = lin >> 6, kl = lin & 63;
            Wt[(size_t)(n0 + nl) * 1024 + k0 + kl] = f2bf(Ts[nl][kl]);
        }
    } else if (bx < 3072) {
        int i = ((bx - 1024) * 256 + tid) * 8;
        float4 a = *(const float4*)(x + i);
        float4 b = *(const float4*)(x + i + 4);
        short8 o;
        o[0] = f2bf(a.x); o[1] = f2bf(a.y); o[2] = f2bf(a.z); o[3] = f2bf(a.w);
        o[4] = f2bf(b.x); o[5] = f2bf(b.y); o[6] = f2bf(b.z); o[7] = f2bf(b.w);
        *(short8*)(xb + i) = o;
    } else {
#pragma unroll
        for (int j = 0; j < 12; ++j) {
            int i = j * 256 + tid;
            float v = (i < 1024) ? bq[i] : ((i < 2048) ? bk[i - 1024] : bv[i - 2048]);
            bqkv[i] = v;
        }
    }
}

// ---------------------------------------------------------------------------
// MFMA GEMM (QKV): C[M][N] = A @ Bt^T + bias. 128x128 tile, BK=32, 4 waves.
// cols < qcols scaled by 0.125*log2(e) (softmax fold, exp2 domain).
// Block-cols >= 2048 are the V projection: written transposed to Vt[b][h][d][t].
// ---------------------------------------------------------------------------
#define QSCALE 0.18033688f   // 0.125 * log2(e)

__global__ __launch_bounds__(256) void gemm_mfma_kernel(
    const unsigned short* __restrict__ A, const unsigned short* __restrict__ Bt,
    const float* __restrict__ bias, unsigned short* __restrict__ Cout,
    unsigned short* __restrict__ Vt, int N, int K, int qcols)
{
    __shared__ __align__(16) unsigned short As[128 * 32];
    __shared__ __align__(16) unsigned short Bs[128 * 32];

    const int tid  = threadIdx.x;
    const int lane = tid & 63;
    const int ln   = lane & 15;
    const int qd   = lane >> 4;
    const int w    = tid >> 6;
    const int wm   = w >> 1, wn = w & 1;

    const int lin  = blockIdx.y * gridDim.x + blockIdx.x;
    const int xcd  = lin & 7;
    const int slot = lin >> 3;
    const int sxw  = gridDim.x >> 1;
    const int syw  = ((gridDim.x * gridDim.y) >> 3) / sxw;
    const int sx   = slot % sxw, sy = slot / sxw;
    const int row0 = ((xcd >> 1) * syw + sy) * 128;
    const int col0 = ((xcd & 1) * sxw + sx) * 128;

    f32x4 acc[4][4];
#pragma unroll
    for (int mi = 0; mi < 4; ++mi)
#pragma unroll
        for (int ni = 0; ni < 4; ++ni)
            acc[mi][ni] = (f32x4){0.f, 0.f, 0.f, 0.f};

    const int s0 = tid, s1 = tid + 256;
    const int rA0 = s0 >> 2, cA0 = (s0 & 3) ^ ((rA0 >> 1) & 3);
    const int rA1 = s1 >> 2, cA1 = (s1 & 3) ^ ((rA1 >> 1) & 3);
    const unsigned short* Ag0 = A + (size_t)(row0 + rA0) * K + cA0 * 8;
    const unsigned short* Ag1 = A + (size_t)(row0 + rA1) * K + cA1 * 8;
    const unsigned short* Bg0 = Bt + (size_t)(col0 + rA0) * K + cA0 * 8;
    const unsigned short* Bg1 = Bt + (size_t)(col0 + rA1) * K + cA1 * 8;
    unsigned short* AsL0 = As + s0 * 8;
    unsigned short* AsL1 = As + s1 * 8;
    unsigned short* BsL0 = Bs + s0 * 8;
    unsigned short* BsL1 = Bs + s1 * 8;

    for (int kb = 0; kb < K; kb += 32) {
        if (kb) __syncthreads();
        gload16(Ag0 + kb, AsL0);
        gload16(Ag1 + kb, AsL1);
        gload16(Bg0 + kb, BsL0);
        gload16(Bg1 + kb, BsL1);
        __builtin_amdgcn_s_waitcnt(0);
        __syncthreads();

        short8 af[4], bf[4];
#pragma unroll
        for (int i = 0; i < 4; ++i) {
            int ra = wm * 64 + i * 16 + ln;
            int pa = ra * 4 + (qd ^ ((ra >> 1) & 3));
            af[i] = *(const short8*)(As + pa * 8);
            int rb = wn * 64 + i * 16 + ln;
            int pb = rb * 4 + (qd ^ ((rb >> 1) & 3));
            bf[i] = *(const short8*)(Bs + pb * 8);
        }
#pragma unroll
        for (int mi = 0; mi < 4; ++mi)
#pragma unroll
            for (int ni = 0; ni < 4; ++ni)
                acc[mi][ni] = __builtin_amdgcn_mfma_f32_16x16x32_bf16(
                    af[mi], bf[ni], acc[mi][ni], 0, 0, 0);
    }

    float bv[4];
#pragma unroll
    for (int ni = 0; ni < 4; ++ni)
        bv[ni] = bias[col0 + wn * 64 + ni * 16 + ln];

    if (col0 >= 2048) {
        const int h = ((col0 - 2048) >> 6) + wn;
#pragma unroll
        for (int mi = 0; mi < 4; ++mi) {
            int row = row0 + wm * 64 + mi * 16 + qd * 4;
            int b = row >> 11, t = row & 2047;
#pragma unroll
            for (int ni = 0; ni < 4; ++ni) {
                int d = ni * 16 + ln;
                float v0 = acc[mi][ni][0] + bv[ni];
                float v1 = acc[mi][ni][1] + bv[ni];
                float v2 = acc[mi][ni][2] + bv[ni];
                float v3 = acc[mi][ni][3] + bv[ni];
                unsigned u0 = pack_bf16x2(v0, v1);
                unsigned u1 = pack_bf16x2(v2, v3);
                *(uint2*)(Vt + (size_t)((b * 16 + h) * 64 + d) * TT + t) =
                    make_uint2(u0, u1);
            }
        }
    } else {
        float scl[4];
#pragma unroll
        for (int ni = 0; ni < 4; ++ni)
            scl[ni] = (col0 + wn * 64 + ni * 16 < qcols) ? QSCALE : 1.0f;
#pragma unroll
        for (int mi = 0; mi < 4; ++mi)
#pragma unroll
            for (int ni = 0; ni < 4; ++ni)
#pragma unroll
                for (int r = 0; r < 4; ++r) {
                    float v = (acc[mi][ni][r] + bv[ni]) * scl[ni];
                    int row = row0 + wm * 64 + mi * 16 + qd * 4 + r;
                    int col = col0 + wn * 64 + ni * 16 + ln;
                    Cout[(size_t)row * N + col] = f2bf(v);
                }
    }
}

// ---------------------------------------------------------------------------
// MFMA GEMM (output proj): 128x64 tile -> 512 blocks (2/CU). fp32 out.
// ---------------------------------------------------------------------------
__global__ __launch_bounds__(256) void gemm_mfma_n64_kernel(
    const unsigned short* __restrict__ A, const unsigned short* __restrict__ Bt,
    const float* __restrict__ bias, float* __restrict__ Cout, int N, int K)
{
    __shared__ __align__(16) unsigned short As[128 * 32];
    __shared__ __align__(16) unsigned short Bs[64 * 32];

    const int tid  = threadIdx.x;
    const int lane = tid & 63;
    const int ln   = lane & 15;
    const int qd   = lane >> 4;
    const int w    = tid >> 6;

    const int lin  = blockIdx.y * gridDim.x + blockIdx.x;
    const int xcd  = lin & 7;
    const int slot = lin >> 3;
    const int sxw  = gridDim.x >> 1;
    const int syw  = ((gridDim.x * gridDim.y) >> 3) / sxw;
    const int sx   = slot % sxw, sy = slot / sxw;
    const int row0 = ((xcd >> 1) * syw + sy) * 128;
    const int col0 = ((xcd & 1) * sxw + sx) * 64;

    f32x4 acc[2][4];
#pragma unroll
    for (int mi = 0; mi < 2; ++mi)
#pragma unroll
        for (int ni = 0; ni < 4; ++ni)
            acc[mi][ni] = (f32x4){0.f, 0.f, 0.f, 0.f};

    const int s0 = tid, s1 = tid + 256;
    const int rA0 = s0 >> 2, cA0 = (s0 & 3) ^ ((rA0 >> 1) & 3);
    const int rA1 = s1 >> 2, cA1 = (s1 & 3) ^ ((rA1 >> 1) & 3);
    const unsigned short* Ag0 = A + (size_t)(row0 + rA0) * K + cA0 * 8;
    const unsigned short* Ag1 = A + (size_t)(row0 + rA1) * K + cA1 * 8;
    const unsigned short* Bg0 = Bt + (size_t)(col0 + rA0) * K + cA0 * 8;
    unsigned short* AsL0 = As + s0 * 8;
    unsigned short* AsL1 = As + s1 * 8;
    unsigned short* BsL0 = Bs + s0 * 8;

    for (int kb = 0; kb < K; kb += 32) {
        if (kb) __syncthreads();
        gload16(Ag0 + kb, AsL0);
        gload16(Ag1 + kb, AsL1);
        gload16(Bg0 + kb, BsL0);
        __builtin_amdgcn_s_waitcnt(0);
        __syncthreads();

        short8 af[2], bf[4];
#pragma unroll
        for (int i = 0; i < 2; ++i) {
            int ra = w * 32 + i * 16 + ln;
            int pa = ra * 4 + (qd ^ ((ra >> 1) & 3));
            af[i] = *(const short8*)(As + pa * 8);
        }
#pragma unroll
        for (int i = 0; i < 4; ++i) {
            int rb = i * 16 + ln;
            int pb = rb * 4 + (qd ^ ((rb >> 1) & 3));
            bf[i] = *(const short8*)(Bs + pb * 8);
        }
#pragma unroll
        for (int mi = 0; mi < 2; ++mi)
#pragma unroll
            for (int ni = 0; ni < 4; ++ni)
                acc[mi][ni] = __builtin_amdgcn_mfma_f32_16x16x32_bf16(
                    af[mi], bf[ni], acc[mi][ni], 0, 0, 0);
    }

    float bv[4];
#pragma unroll
    for (int ni = 0; ni < 4; ++ni)
        bv[ni] = bias[col0 + ni * 16 + ln];

#pragma unroll
    for (int mi = 0; mi < 2; ++mi)
#pragma unroll
        for (int ni = 0; ni < 4; ++ni)
#pragma unroll
            for (int r = 0; r < 4; ++r) {
                int row = row0 + w * 32 + mi * 16 + qd * 4 + r;
                int col = col0 + ni * 16 + ln;
                Cout[(size_t)row * N + col] = acc[mi][ni][r] + bv[ni];
            }
}

// ---------------------------------------------------------------------------
// Flash attention: pair-of-tiles per block (balanced 33 chunks), XCD-pinned,
// exp2-domain softmax, K-fragment SOFTWARE PIPELINE (prefetch next chunk's
// kf during current chunk's softmax+PV -- removes exposed K load latency;
// r8 counters: 5800 cyc/chunk vs ~1500 compute => latency-exposed).
// Natural register allocation (caps spill -- r5/r6).
// ---------------------------------------------------------------------------
#define PSTRIDE 136
#define LDS_TOTAL (4*64*PSTRIDE + 2048)

__global__ __launch_bounds__(256) void attn_mfma_kernel(
    const unsigned short* __restrict__ QKV,
    const unsigned short* __restrict__ Vt,
    unsigned short* __restrict__ Aout)
{
    __shared__ __align__(16) unsigned char lds[LDS_TOTAL];

    const int tid  = threadIdx.x;
    const int lane = tid & 63;
    const int ln   = lane & 15;
    const int qd   = lane >> 4;
    const int qd4  = qd * 4;
    const int w    = tid >> 6;

    // 512 blocks: XCD = bx&7 pinned per bh (4 bh per XCD), p = tile pair idx
    const int bx  = blockIdx.x;
    const int bh  = (bx & 7) + 8 * ((bx >> 3) & 3);
    const int p   = bx >> 5;                 // 0..15
    const int b   = bh >> 4;
    const int h   = bh & 15;

    unsigned char* Pb   = lds + w * (64 * PSTRIDE);
    float*         Oacc = (float*)lds;
    float*         mlm  = (float*)(lds + 4 * 64 * PSTRIDE);
    float*         mll  = mlm + 256;

    const unsigned short* Kh = QKV + 1024 + h * 64;
    const unsigned short* Qh = QKV + h * 64;
    const unsigned short* Vh = Vt + (size_t)((b * 16 + h) * 64) * TT;

    for (int ti = 0; ti < 2; ++ti) {
        const int qt = ti ? p : (31 - p);
        __syncthreads();   // P/Oacc region safe to reuse

        short8 qa[4][2];
        {
            const unsigned short* Qb = Qh + (size_t)(b * TT + qt * 64) * 3072;
#pragma unroll
            for (int q4 = 0; q4 < 4; ++q4)
#pragma unroll
                for (int kk = 0; kk < 2; ++kk)
                    qa[q4][kk] = *(const short8*)(Qb + (size_t)(q4 * 16 + ln) * 3072 + kk * 32 + qd * 8);
        }

        f32x4 O[4][4];
#pragma unroll
        for (int dt = 0; dt < 4; ++dt)
#pragma unroll
            for (int q4 = 0; q4 < 4; ++q4)
                O[dt][q4] = (f32x4){0.f, 0.f, 0.f, 0.f};
        float m_i[4] = {-1e30f, -1e30f, -1e30f, -1e30f};
        float l_i[4] = {0.f, 0.f, 0.f, 0.f};

        // ---- K-fragment pipeline prologue: load kf for first chunk
        short8 kf[4][2];
        {
            const unsigned short* Kc0 = Kh + (size_t)(b * TT + w * 64) * 3072;
#pragma unroll
            for (int kt = 0; kt < 4; ++kt)
#pragma unroll
                for (int kk = 0; kk < 2; ++kk)
                    kf[kt][kk] = *(const short8*)(Kc0 + (size_t)(kt * 16 + ln) * 3072 + kk * 32 + qd * 8);
        }

        for (int kc = w; kc <= qt; kc += 4) {
            const unsigned short* Vc = Vh + kc * 64;

            // V for current chunk: issued now, consumed at the bottom (hidden)
            short8 vf[4][2];
#pragma unroll
            for (int dt = 0; dt < 4; ++dt)
#pragma unroll
                for (int kk = 0; kk < 2; ++kk)
                    vf[dt][kk] = *(const short8*)(Vc + (size_t)(dt * 16 + ln) * TT + kk * 32 + qd * 8);

            // ---- S^T = K Q^T on the prefetched kf
            f32x4 st[4][4];
#pragma unroll
            for (int kt = 0; kt < 4; ++kt)
#pragma unroll
                for (int q4 = 0; q4 < 4; ++q4) {
                    f32x4 a = (f32x4){0.f, 0.f, 0.f, 0.f};
                    a = __builtin_amdgcn_mfma_f32_16x16x32_bf16(kf[kt][0], qa[q4][0], a, 0, 0, 0);
                    a = __builtin_amdgcn_mfma_f32_16x16x32_bf16(kf[kt][1], qa[q4][1], a, 0, 0, 0);
                    st[kt][q4] = a;
                }

            // ---- prefetch next chunk's kf (kf regs now dead until next iter)
            if (kc + 4 <= qt) {
                const unsigned short* Kn = Kh + (size_t)(b * TT + (kc + 4) * 64) * 3072;
#pragma unroll
                for (int kt = 0; kt < 4; ++kt)
#pragma unroll
                    for (int kk = 0; kk < 2; ++kk)
                        kf[kt][kk] = *(const short8*)(Kn + (size_t)(kt * 16 + ln) * 3072 + kk * 32 + qd * 8);
            }

            if (kc == qt) {
#pragma unroll
                for (int kt = 0; kt < 4; ++kt)
#pragma unroll
                    for (int q4 = 0; q4 < 4; ++q4)
#pragma unroll
                        for (int r = 0; r < 4; ++r)
                            if (kt * 16 + qd4 + r > q4 * 16 + ln)
                                st[kt][q4][r] = -1e30f;
            }

            float alpha[4];
#pragma unroll
            for (int q4 = 0; q4 < 4; ++q4) {
                float mx = st[0][q4][0];
#pragma unroll
                for (int kt = 0; kt < 4; ++kt)
#pragma unroll
                    for (int r = 0; r < 4; ++r)
                        mx = fmaxf(mx, st[kt][q4][r]);
                mx = fmaxf(mx, __shfl_xor(mx, 16, 64));
                mx = fmaxf(mx, __shfl_xor(mx, 32, 64));
                float mn = fmaxf(m_i[q4], mx);
                alpha[q4] = exp2f(m_i[q4] - mn);
                m_i[q4] = mn;
            }
#pragma unroll
            for (int kt = 0; kt < 4; ++kt)
#pragma unroll
                for (int q4 = 0; q4 < 4; ++q4)
#pragma unroll
                    for (int r = 0; r < 4; ++r)
                        st[kt][q4][r] = exp2f(st[kt][q4][r] - m_i[q4]);
#pragma unroll
            for (int q4 = 0; q4 < 4; ++q4) {
                float sm = 0.f;
#pragma unroll
                for (int kt = 0; kt < 4; ++kt)
#pragma unroll
                    for (int r = 0; r < 4; ++r)
                        sm += st[kt][q4][r];
                sm += __shfl_xor(sm, 16, 64);
                sm += __shfl_xor(sm, 32, 64);
                l_i[q4] = l_i[q4] * alpha[q4] + sm;
            }
#pragma unroll
            for (int dt = 0; dt < 4; ++dt)
#pragma unroll
                for (int q4 = 0; q4 < 4; ++q4) {
                    O[dt][q4][0] *= alpha[q4]; O[dt][q4][1] *= alpha[q4];
                    O[dt][q4][2] *= alpha[q4]; O[dt][q4][3] *= alpha[q4];
                }

#pragma unroll
            for (int kt = 0; kt < 4; ++kt)
#pragma unroll
                for (int q4 = 0; q4 < 4; ++q4) {
                    unsigned u0 = pack_bf16x2(st[kt][q4][0], st[kt][q4][1]);
                    unsigned u1 = pack_bf16x2(st[kt][q4][2], st[kt][q4][3]);
                    *(uint2*)(Pb + (q4 * 16 + ln) * PSTRIDE + kt * 32 + qd * 8) =
                        make_uint2(u0, u1);
                }

#pragma unroll
            for (int kk = 0; kk < 2; ++kk)
#pragma unroll
                for (int q4 = 0; q4 < 4; ++q4) {
                    union { struct { uint2 a, b; } u; short8 s; } y;
                    const unsigned char* yp = Pb + (q4 * 16 + ln) * PSTRIDE + kk * 64 + qd * 16;
                    y.u.a = *(const uint2*)(yp);
                    y.u.b = *(const uint2*)(yp + 8);
#pragma unroll
                    for (int dt = 0; dt < 4; ++dt)
                        O[dt][q4] = __builtin_amdgcn_mfma_f32_16x16x32_bf16(
                            vf[dt][kk], y.s, O[dt][q4], 0, 0, 0);
                }
        }

        if (qd == 0) {
#pragma unroll
            for (int q4 = 0; q4 < 4; ++q4) {
                mlm[w * 64 + q4 * 16 + ln] = m_i[q4];
                mll[w * 64 + q4 * 16 + ln] = l_i[q4];
            }
        }
        __syncthreads();

        float fac[4];
#pragma unroll
        for (int q4 = 0; q4 < 4; ++q4) {
            int q = q4 * 16 + ln;
            float m0 = mlm[q], m1 = mlm[64 + q], m2 = mlm[128 + q], m3 = mlm[192 + q];
            float M = fmaxf(fmaxf(m0, m1), fmaxf(m2, m3));
            float f0 = exp2f(m0 - M), f1 = exp2f(m1 - M);
            float f2 = exp2f(m2 - M), f3 = exp2f(m3 - M);
            float L = f0 * mll[q] + f1 * mll[64 + q] + f2 * mll[128 + q] + f3 * mll[192 + q];
            float myf = (w == 0) ? f0 : (w == 1) ? f1 : (w == 2) ? f2 : f3;
            fac[q4] = myf / L;
        }
#pragma unroll
        for (int dt = 0; dt < 4; ++dt)
#pragma unroll
            for (int q4 = 0; q4 < 4; ++q4) {
                O[dt][q4][0] *= fac[q4]; O[dt][q4][1] *= fac[q4];
                O[dt][q4][2] *= fac[q4]; O[dt][q4][3] *= fac[q4];
            }

        for (int wv = 0; wv < 4; ++wv) {
            if (w == wv) {
#pragma unroll
                for (int dt = 0; dt < 4; ++dt)
#pragma unroll
                    for (int q4 = 0; q4 < 4; ++q4) {
                        float* pp = Oacc + (q4 * 16 + ln) * 68 + dt * 16 + qd4;
                        if (wv == 0) {
                            *(f32x4*)pp = O[dt][q4];
                        } else {
                            f32x4 t = *(const f32x4*)pp;
                            t += O[dt][q4];
                            *(f32x4*)pp = t;
                        }
                    }
            }
            __syncthreads();
        }

        {
            int q = tid >> 2, dg = tid & 3;
            const float* rowp = Oacc + q * 68 + dg * 16;
            short8 s0v, s1v;
#pragma unroll
            for (int i = 0; i < 8; ++i) {
                s0v[i] = f2bf(rowp[i]);
                s1v[i] = f2bf(rowp[8 + i]);
            }
            size_t orow = (size_t)(b * TT + qt * 64 + q) * D_MODEL + h * 64 + dg * 16;
            *(short8*)(Aout + orow) = s0v;
            *(short8*)(Aout + orow + 8) = s1v;
        }
    }
}

// ---------------------------------------------------------------------------
extern "C" void kernel_launch(void* const* d_in, const int* in_sizes, int n_in,
                              void* d_out, int out_size, void* d_ws, size_t ws_size,
                              hipStream_t stream) {
    const float* x  = (const float*)d_in[0];
    const float* Wq = (const float*)d_in[2];
    const float* bq = (const float*)d_in[3];
    const float* Wk = (const float*)d_in[4];
    const float* bk = (const float*)d_in[5];
    const float* Wv = (const float*)d_in[6];
    const float* bv = (const float*)d_in[7];
    const float* Wo = (const float*)d_in[8];
    const float* bo = (const float*)d_in[9];
    float* out = (float*)d_out;

    uint8_t* w8 = (uint8_t*)d_ws;
    const size_t MB = 1024 * 1024;
    unsigned short* xb    = (unsigned short*)(w8);                 // 8 MB [4096][1024]
    unsigned short* Wqkvt = (unsigned short*)(w8 + 8 * MB);        // 6 MB [3072][1024]
    unsigned short* Wot   = (unsigned short*)(w8 + 14 * MB);       // 2 MB [1024][1024]
    float*          bqkv  = (float*)(w8 + 16 * MB);                // 12 KB
    unsigned short* QKV   = (unsigned short*)(w8 + 17 * MB);       // 24 MB [4096][3072] (V region unused)
    unsigned short* Vt    = (unsigned short*)(w8 + 41 * MB);       // 8 MB [2][16][64][2048]
    unsigned short* Aout  = (unsigned short*)(w8 + 49 * MB);       // 8 MB [4096][1024]

    prep_kernel<<<3073, 256, 0, stream>>>(x, Wq, Wk, Wv, Wo, bq, bk, bv,
                                          xb, Wqkvt, Wot, bqkv);
    gemm_mfma_kernel<<<dim3(24, 32), 256, 0, stream>>>(xb, Wqkvt, bqkv, QKV, Vt,
                                                       3072, 1024, 1024);
    attn_mfma_kernel<<<512, 256, 0, stream>>>(QKV, Vt, Aout);
    gemm_mfma_n64_kernel<<<dim3(16, 32), 256, 0, stream>>>(Aout, Wot, bo, out,
                                                           1024, 1024);
}